// Round 6
// baseline (240.537 us; speedup 1.0000x reference)
//
#include <hip/hip_runtime.h>

// Problem constants (reference: B,S,M,D,NQ = 128,100,50,128,10000)
#define BB 128
#define SS 100
#define MM 50
#define DD 128
#define KROW 66                        // key row stride (u32 words), no overlap

typedef float f32x2 __attribute__((ext_vector_type(2)));

#if defined(__has_builtin)
#  if __has_builtin(__builtin_elementwise_fma)
#    define HAVE_PKFMA 1
#  endif
#  if __has_builtin(__builtin_amdgcn_update_dpp)
#    define HAVE_DPP 1
#  endif
#  if __has_builtin(__builtin_amdgcn_rcpf)
#    define HAVE_RCP 1
#  endif
#  if __has_builtin(__builtin_amdgcn_exp2f)
#    define EXP2(x) __builtin_amdgcn_exp2f(x)
#  endif
#  if __has_builtin(__builtin_amdgcn_fdot2_f32_bf16)
#    define HAVE_DOT2BF 1
#  endif
#endif
#ifndef EXP2
#  define EXP2(x) exp2f(x)
#endif

__device__ __forceinline__ f32x2 pkfma(f32x2 a, f32x2 b, f32x2 c) {
#ifdef HAVE_PKFMA
    return __builtin_elementwise_fma(a, b, c);
#else
    f32x2 r; r.x = fmaf(a.x, b.x, c.x); r.y = fmaf(a.y, b.y, c.y); return r;
#endif
}

__device__ __forceinline__ float qbf_add(float x) {
#ifdef HAVE_DPP
    union { float f; int i; } c, o;
    c.f = x;
    o.i = __builtin_amdgcn_update_dpp(0, c.i, 0xB1, 0xF, 0xF, true);  // quad_perm(1,0,3,2)
    x += o.f;
    c.f = x;
    o.i = __builtin_amdgcn_update_dpp(0, c.i, 0x4E, 0xF, 0xF, true);  // quad_perm(2,3,0,1)
    return x + o.f;
#else
    x += __shfl_xor(x, 1);
    x += __shfl_xor(x, 2);
    return x;
#endif
}

// Block-wide barrier WITHOUT the vmcnt(0) drain that __syncthreads() implies.
__device__ __forceinline__ void barrier_lgkm() {
    asm volatile("s_waitcnt lgkmcnt(0)" ::: "memory");
    __builtin_amdgcn_s_barrier();
    __builtin_amdgcn_sched_barrier(0);   // keep post-barrier ds_reads below the barrier
}

// ---- bf16 helpers ----
__device__ __forceinline__ float bf2f(unsigned short u) {
    union { unsigned int i; float f; } c; c.i = ((unsigned int)u) << 16; return c.f;
}
__device__ __forceinline__ float bfu_lo(unsigned int u) {
    union { unsigned int i; float f; } c; c.i = u << 16; return c.f;
}
__device__ __forceinline__ float bfu_hi(unsigned int u) {
    union { unsigned int i; float f; } c; c.i = u & 0xffff0000u; return c.f;
}
__device__ __forceinline__ unsigned short f2bf_bits(float f) {   // RNE
    union { float f; unsigned int u; } c; c.f = f;
    unsigned int r = (c.u + 0x7FFFu + ((c.u >> 16) & 1u)) >> 16;
    return (unsigned short)r;
}
__device__ __forceinline__ unsigned int packbf(float lo, float hi) {
    return (unsigned int)f2bf_bits(lo) | ((unsigned int)f2bf_bits(hi) << 16);
}
// HW bf16 convert (single v_cvt) where available; software RNE otherwise.
__device__ __forceinline__ unsigned short f2bf_hw(float f) {
#ifdef HAVE_DOT2BF
    union { __bf16 b; unsigned short u; } c; c.b = (__bf16)f; return c.u;
#else
    return f2bf_bits(f);
#endif
}
// v_rcp_f32 (~1 ULP) instead of IEEE divide chain.
__device__ __forceinline__ float fast_rcp(float x) {
#ifdef HAVE_RCP
    return __builtin_amdgcn_rcpf(x);
#else
    return 1.0f / x;
#endif
}
__device__ __forceinline__ float fast_sigmoid(float x) {
    return fast_rcp(1.0f + EXP2(x * -1.4426950408889634f));
}
// 2-term tanh: tanh(x) = 1 - 2/(1+e^{2x}).  Chain: mul -> exp2 -> add -> rcp
// -> fma (no fabs/sub/copysign).  Saturation-safe: exp2 -> inf gives +1,
// exp2 -> 0 gives -1; never NaN.
__device__ __forceinline__ float fast_tanh(float x) {
    return fmaf(-2.0f, fast_rcp(1.0f + EXP2(x * 2.8853900817779268f)), 1.0f);
}

#ifdef HAVE_DOT2BF
typedef __bf16 bf2v __attribute__((ext_vector_type(2)));
__device__ __forceinline__ bf2v u2bf(unsigned int u) {
    union { unsigned int x; bf2v v; } c; c.x = u; return c.v;
}
// full-rate 2-way bf16 dot with f32 accumulate: v_dot2_f32_bf16
__device__ __forceinline__ float dot2bf(unsigned int a, unsigned int b, float c) {
    return __builtin_amdgcn_fdot2_f32_bf16(u2bf(a), u2bf(b), c, false);
}
#endif

template <bool BF16>
__device__ __forceinline__ float ldw(const void* p, size_t idx) {
    if (BF16) return bf2f(((const unsigned short*)p)[idx]);
    return ((const float*)p)[idx];
}

__device__ __forceinline__ bool detect_bf16(const void* emb) {
    const unsigned int* eu = (const unsigned int*)emb;
    int cnt = 0;
    for (int i = 0; i < 32; ++i) {
        unsigned int e8 = (eu[i] >> 7) & 0xFFu;
        cnt += (e8 >= 100u && e8 <= 127u) ? 1 : 0;
    }
    return cnt >= 16;
}

#define W2ROW(r) ((r) * 68 + (((r) >> 5) << 3))

// ---- workspace layout (bytes) ----
#define WS_WROW_OFF 0u
#define WS_QP_OFF   (BB * SS * 32u * 4u)                 // 1,638,400
#define WS_W2EA_OFF (WS_QP_OFF + BB * SS * DD * 2u)      // 4,915,200
#define WS_EAB_OFF  (WS_W2EA_OFF + DD * DD * 8u)         // 5,046,272
#define WS_NEED     (WS_EAB_OFF + DD * 8u)               // 5,047,296

// =====================================================================
// Kernel A: grid (129, 2) x 512. Blocks (b<128, half): attention softmax +
// qe-projection for s in [50*half, 50*half+50). Block (128,0): W2EA build.
// =====================================================================
struct __align__(16) SmemA {
    union {
        struct {
            unsigned int key_w[MM * KROW];
            unsigned int qe8[8][68];
        } pre;
        unsigned int w2s[8724];
    } u;
};

template <bool BF16>
__device__ void pre_impl(const int* qseq, const void* emb, const void* key,
                         const void* vu_w1, unsigned int* wrow_g, unsigned short* qp_g,
                         SmemA& sm)
{
    const int t = threadIdx.x;
    const int b = blockIdx.x;
    const int half = blockIdx.y;
    const int l = t & 63;
    const int wv = t >> 6;
    const int q = l & 3;
    const int d = (wv << 4) + (l >> 2);

    if (BF16) {
        const unsigned int* kg = (const unsigned int*)key;
        for (int g = t; g < MM * 64; g += 512)
            sm.u.pre.key_w[(g >> 6) * KROW + (g & 63)] = kg[g];
    } else {
        const float* kf = (const float*)key;
        for (int g = t; g < MM * 64; g += 512) {
            int row = g >> 6, c2 = g & 63;
            sm.u.pre.key_w[row * KROW + c2] = packbf(kf[row * 128 + 2 * c2], kf[row * 128 + 2 * c2 + 1]);
        }
    }

    float rw1b[32];
#pragma unroll
    for (int i = 0; i < 32; ++i)
        rw1b[i] = ldw<BF16>(vu_w1, (size_t)(DD + 32 * q + i) * DD + d);
    __syncthreads();

    for (int ii = 0; ii < 7; ++ii) {
        const int nrows = (ii == 6) ? 2 : 8;
        {
            int r = t >> 6, w = t & 63;
            if (r < nrows) {
                int s = 50 * half + 8 * ii + r;
                int row = qseq[b * SS + s];
                if (BF16) {
                    sm.u.pre.qe8[r][w] = ((const unsigned int*)emb)[((size_t)row << 6) + w];
                } else {
                    const float* ef = (const float*)emb + (((size_t)row) << 7) + 2 * w;
                    sm.u.pre.qe8[r][w] = packbf(ef[0], ef[1]);
                }
            }
        }
        __syncthreads();

        if (wv < nrows) {
            int m = l;
            int mc = (m < MM) ? m : (MM - 1);
            float a0 = 0.f, a1 = 0.f, a2 = 0.f, a3 = 0.f;
#pragma unroll
            for (int j = 0; j < 32; ++j) {
                uint2 kw = *(const uint2*)&sm.u.pre.key_w[mc * KROW + 2 * j];
                uint2 qw = *(const uint2*)&sm.u.pre.qe8[wv][2 * j];
                a0 = fmaf(bfu_lo(kw.x), bfu_lo(qw.x), a0);
                a1 = fmaf(bfu_hi(kw.x), bfu_hi(qw.x), a1);
                a2 = fmaf(bfu_lo(kw.y), bfu_lo(qw.y), a2);
                a3 = fmaf(bfu_hi(kw.y), bfu_hi(qw.y), a3);
            }
            float lg = (a0 + a1) + (a2 + a3);
            if (m >= MM) lg = -1e30f;
            float mx = lg;
#pragma unroll
            for (int o = 32; o > 0; o >>= 1) mx = fmaxf(mx, __shfl_xor(mx, o));
            float p = (m < MM) ? __expf(lg - mx) : 0.f;
            float sum = p;
#pragma unroll
            for (int o = 32; o > 0; o >>= 1) sum += __shfl_xor(sum, o);
            p = p * fast_rcp(sum);
            float pn = __shfl_xor(p, 4);
            int s = 50 * half + 8 * ii + wv;
            if ((m & 4) == 0)
                wrow_g[(size_t)(b * SS + s) * 32 + (m & 3) * 8 + (m >> 3)] = packbf(p, pn);
        }

        for (int sr = 0; sr < nrows; ++sr) {
            float p0 = 0.f, p1 = 0.f;
#pragma unroll
            for (int i = 0; i < 16; ++i) {
                unsigned int uw = sm.u.pre.qe8[sr][16 * q + i];
                p0 = fmaf(rw1b[2 * i],     bfu_lo(uw), p0);
                p1 = fmaf(rw1b[2 * i + 1], bfu_hi(uw), p1);
            }
            float qpv = qbf_add(p0 + p1);
            int s = 50 * half + 8 * ii + sr;
            if (q == 0) qp_g[(size_t)(b * SS + s) * DD + d] = f2bf_bits(qpv);
        }
        __syncthreads();
    }
}

template <bool BF16>
__device__ void build_impl(const void* vu_w2, const void* vu_b2,
                           const void* er_w, const void* er_b,
                           const void* ad_w, const void* ad_b,
                           f32x2* w2ea_g, f32x2* eab_g, SmemA& sm)
{
    const int t = threadIdx.x;
    const int l = t & 63;
    const int wv = t >> 6;
    const int q = l & 3;
    const int d = (wv << 4) + (l >> 2);

    if (BF16) {
        const unsigned int* wg = (const unsigned int*)vu_w2;
        for (int g = t; g < 128 * 64; g += 512)
            sm.u.w2s[W2ROW(g >> 6) + (g & 63)] = wg[g];
    } else {
        const float* wf = (const float*)vu_w2;
        for (int g = t; g < 128 * 64; g += 512) {
            int row = g >> 6, c2 = g & 63;
            sm.u.w2s[W2ROW(row) + c2] = packbf(wf[row * 128 + 2 * c2], wf[row * 128 + 2 * c2 + 1]);
        }
    }
    __syncthreads();

    f32x2 rw2ea[32];
#pragma unroll
    for (int k = 0; k < 32; ++k) { rw2ea[k].x = 0.f; rw2ea[k].y = 0.f; }
    f32x2 eab2; eab2.x = 0.f; eab2.y = 0.f;
#pragma unroll 1
    for (int jc = 0; jc < 4; ++jc) {
        f32x2 ea[32];
#pragma unroll
        for (int i = 0; i < 32; ++i) {
            int j = 32 * jc + i;
            ea[i].x = ldw<BF16>(er_w, (size_t)j * DD + d);
            ea[i].y = ldw<BF16>(ad_w, (size_t)j * DD + d);
            float b2j = ldw<BF16>(vu_b2, j);
            f32x2 bs; bs.x = b2j; bs.y = b2j;
            eab2 = pkfma(bs, ea[i], eab2);
        }
#pragma unroll
        for (int k = 0; k < 32; ++k) {
            const uint4* wp = (const uint4*)&sm.u.w2s[W2ROW(32 * q + k) + 16 * jc];
            uint4 A = wp[0], B = wp[1], C = wp[2], Dv = wp[3];
            unsigned int W[16] = { A.x, A.y, A.z, A.w, B.x, B.y, B.z, B.w,
                                   C.x, C.y, C.z, C.w, Dv.x, Dv.y, Dv.z, Dv.w };
            f32x2 acc = rw2ea[k];
#pragma unroll
            for (int wd = 0; wd < 16; ++wd) {
                float wlo = bfu_lo(W[wd]), whi = bfu_hi(W[wd]);
                f32x2 s0; s0.x = wlo; s0.y = wlo;
                f32x2 s1; s1.x = whi; s1.y = whi;
                acc = pkfma(s0, ea[2 * wd], acc);
                acc = pkfma(s1, ea[2 * wd + 1], acc);
            }
            rw2ea[k] = acc;
        }
    }
    eab2.x += ldw<BF16>(er_b, d);
    eab2.y += ldw<BF16>(ad_b, d);

#pragma unroll
    for (int k = 0; k < 32; ++k)
        w2ea_g[(size_t)(32 * q + k) * DD + d] = rw2ea[k];
    if (q == 0) eab_g[d] = eab2;
}

__global__ __launch_bounds__(512) void DKVMN_78546361909953_pre(
    const int* __restrict__ qseq,
    const void* emb, const void* key, const void* vu_w1,
    const void* vu_w2, const void* vu_b2,
    const void* er_w, const void* er_b, const void* ad_w, const void* ad_b,
    void* ws)
{
    __shared__ SmemA sm;
    unsigned int*   wrow_g = (unsigned int*)((char*)ws + WS_WROW_OFF);
    unsigned short* qp_g   = (unsigned short*)((char*)ws + WS_QP_OFF);
    f32x2*          w2ea_g = (f32x2*)((char*)ws + WS_W2EA_OFF);
    f32x2*          eab_g  = (f32x2*)((char*)ws + WS_EAB_OFF);
    bool isbf = detect_bf16(emb);
    if (blockIdx.x < BB) {
        if (isbf) pre_impl<true>(qseq, emb, key, vu_w1, wrow_g, qp_g, sm);
        else      pre_impl<false>(qseq, emb, key, vu_w1, wrow_g, qp_g, sm);
    } else if (blockIdx.y == 0) {
        if (isbf) build_impl<true>(vu_w2, vu_b2, er_w, er_b, ad_w, ad_b, w2ea_g, eab_g, sm);
        else      build_impl<false>(vu_w2, vu_b2, er_w, er_b, ad_w, ad_b, w2ea_g, eab_g, sm);
    }
}

// =====================================================================
// Kernel B: 128 blocks x 512. Chain-trimmed scan:
//  - direct per-step table reads: qptab[s] at E-top, wtabf[s]/[s+1] at
//    G-top (latency hidden under the phase-top x/h reads). No prefetch
//    carry, no w double-buffer, no role-swap unroll; last step peeled.
//  - 2-term tanh (1 - 2*rcp(1+exp2(2log2e*x))): shorter chain, used 2x/step.
//  - dot2 GEMVs, bf16 x/h exchange, scalar-FMA state ops (round-4 core).
// =====================================================================
struct __align__(16) SmemB {
    unsigned short xread[144];       // bf16 read vector (128 + pad)
    unsigned short xh[144];          // bf16 h vector
    float h1f[DD];
    float qlast[DD];
    f32x2 wtabf[SS][32];             // expanded attention rows, 25.6 KB
    unsigned short qptab[SS][DD];    // per-step qe-projection (bf16), 25.6 KB
};

// ---- per-path GEMV cores (textual macros; expand inside scan_impl) ----
#ifdef HAVE_DOT2BF
#define SCAN_E(S)                                                           \
    {                                                                       \
        float hb_ = bf2f(sm.qptab[(S)][d]) + b1r;                           \
        const uint4* xp_ = (const uint4*)&sm.xread[32 * q];                 \
        uint4 X0 = xp_[0], X1 = xp_[1], X2 = xp_[2], X3 = xp_[3];           \
        float a0_ = dot2bf(rw1p[0],  X0.x, hb_ * 0.25f);                    \
        float a1_ = dot2bf(rw1p[1],  X0.y, 0.f);                            \
        float a2_ = dot2bf(rw1p[2],  X0.z, 0.f);                            \
        float a3_ = dot2bf(rw1p[3],  X0.w, 0.f);                            \
        a0_ = dot2bf(rw1p[4],  X1.x, a0_);                                  \
        a1_ = dot2bf(rw1p[5],  X1.y, a1_);                                  \
        a2_ = dot2bf(rw1p[6],  X1.z, a2_);                                  \
        a3_ = dot2bf(rw1p[7],  X1.w, a3_);                                  \
        a0_ = dot2bf(rw1p[8],  X2.x, a0_);                                  \
        a1_ = dot2bf(rw1p[9],  X2.y, a1_);                                  \
        a2_ = dot2bf(rw1p[10], X2.z, a2_);                                  \
        a3_ = dot2bf(rw1p[11], X2.w, a3_);                                  \
        a0_ = dot2bf(rw1p[12], X3.x, a0_);                                  \
        a1_ = dot2bf(rw1p[13], X3.y, a1_);                                  \
        a2_ = dot2bf(rw1p[14], X3.z, a2_);                                  \
        a3_ = dot2bf(rw1p[15], X3.w, a3_);                                  \
        float u_ = qbf_add((a0_ + a1_) + (a2_ + a3_));                      \
        float hh_ = fast_tanh(u_);                                          \
        if (q == 0) sm.xh[d] = f2bf_hw(hh_);                                \
    }
#define SCAN_G_ACC                                                          \
        const uint4* hp_ = (const uint4*)&sm.xh[32 * q];                    \
        uint4 H0 = hp_[0], H1 = hp_[1], H2 = hp_[2], H3 = hp_[3];           \
        float e0_ = dot2bf(rwep[0],  H0.x, eab2.x * 0.25f);                 \
        float g0_ = dot2bf(rwap[0],  H0.x, eab2.y * 0.25f);                 \
        float e1_ = dot2bf(rwep[1],  H0.y, 0.f);                            \
        float g1_ = dot2bf(rwap[1],  H0.y, 0.f);                            \
        float e2_ = dot2bf(rwep[2],  H0.z, 0.f);                            \
        float g2_ = dot2bf(rwap[2],  H0.z, 0.f);                            \
        float e3_ = dot2bf(rwep[3],  H0.w, 0.f);                            \
        float g3_ = dot2bf(rwap[3],  H0.w, 0.f);                            \
        e0_ = dot2bf(rwep[4],  H1.x, e0_);  g0_ = dot2bf(rwap[4],  H1.x, g0_); \
        e1_ = dot2bf(rwep[5],  H1.y, e1_);  g1_ = dot2bf(rwap[5],  H1.y, g1_); \
        e2_ = dot2bf(rwep[6],  H1.z, e2_);  g2_ = dot2bf(rwap[6],  H1.z, g2_); \
        e3_ = dot2bf(rwep[7],  H1.w, e3_);  g3_ = dot2bf(rwap[7],  H1.w, g3_); \
        e0_ = dot2bf(rwep[8],  H2.x, e0_);  g0_ = dot2bf(rwap[8],  H2.x, g0_); \
        e1_ = dot2bf(rwep[9],  H2.y, e1_);  g1_ = dot2bf(rwap[9],  H2.y, g1_); \
        e2_ = dot2bf(rwep[10], H2.z, e2_);  g2_ = dot2bf(rwap[10], H2.z, g2_); \
        e3_ = dot2bf(rwep[11], H2.w, e3_);  g3_ = dot2bf(rwap[11], H2.w, g3_); \
        e0_ = dot2bf(rwep[12], H3.x, e0_);  g0_ = dot2bf(rwap[12], H3.x, g0_); \
        e1_ = dot2bf(rwep[13], H3.y, e1_);  g1_ = dot2bf(rwap[13], H3.y, g1_); \
        e2_ = dot2bf(rwep[14], H3.z, e2_);  g2_ = dot2bf(rwap[14], H3.z, g2_); \
        e3_ = dot2bf(rwep[15], H3.w, e3_);  g3_ = dot2bf(rwap[15], H3.w, g3_); \
        float ae_ = qbf_add((e0_ + e1_) + (e2_ + e3_));                     \
        float aa_ = qbf_add((g0_ + g1_) + (g2_ + g3_));
#else
#define SCAN_E(S)                                                           \
    {                                                                       \
        float hb_ = bf2f(sm.qptab[(S)][d]) + b1r;                           \
        const uint4* xp_ = (const uint4*)&sm.xread[32 * q];                 \
        uint4 X0 = xp_[0], X1 = xp_[1], X2 = xp_[2], X3 = xp_[3];           \
        unsigned int XW_[16] = { X0.x, X0.y, X0.z, X0.w, X1.x, X1.y, X1.z, X1.w, \
                                 X2.x, X2.y, X2.z, X2.w, X3.x, X3.y, X3.z, X3.w }; \
        float a0_ = hb_ * 0.25f, a1_ = 0.f, a2_ = 0.f, a3_ = 0.f;           \
        _Pragma("unroll")                                                   \
        for (int i_ = 0; i_ < 4; ++i_) {                                    \
            a0_ = fmaf(rw1a[8 * i_ + 0], bfu_lo(XW_[4 * i_ + 0]), a0_);     \
            a0_ = fmaf(rw1a[8 * i_ + 1], bfu_hi(XW_[4 * i_ + 0]), a0_);     \
            a1_ = fmaf(rw1a[8 * i_ + 2], bfu_lo(XW_[4 * i_ + 1]), a1_);     \
            a1_ = fmaf(rw1a[8 * i_ + 3], bfu_hi(XW_[4 * i_ + 1]), a1_);     \
            a2_ = fmaf(rw1a[8 * i_ + 4], bfu_lo(XW_[4 * i_ + 2]), a2_);     \
            a2_ = fmaf(rw1a[8 * i_ + 5], bfu_hi(XW_[4 * i_ + 2]), a2_);     \
            a3_ = fmaf(rw1a[8 * i_ + 6], bfu_lo(XW_[4 * i_ + 3]), a3_);     \
            a3_ = fmaf(rw1a[8 * i_ + 7], bfu_hi(XW_[4 * i_ + 3]), a3_);     \
        }                                                                   \
        float u_ = qbf_add((a0_ + a1_) + (a2_ + a3_));                      \
        float hh_ = fast_tanh(u_);                                          \
        if (q == 0) sm.xh[d] = f2bf_hw(hh_);                                \
    }
#define SCAN_G_ACC                                                          \
        const uint4* hp_ = (const uint4*)&sm.xh[32 * q];                    \
        uint4 H0 = hp_[0], H1 = hp_[1], H2 = hp_[2], H3 = hp_[3];           \
        unsigned int HW_[16] = { H0.x, H0.y, H0.z, H0.w, H1.x, H1.y, H1.z, H1.w, \
                                 H2.x, H2.y, H2.z, H2.w, H3.x, H3.y, H3.z, H3.w }; \
        float ae_ = eab2.x * 0.25f, aa_ = eab2.y * 0.25f;                   \
        float e1_ = 0.f, g1_ = 0.f;                                         \
        _Pragma("unroll")                                                   \
        for (int i_ = 0; i_ < 16; ++i_) {                                   \
            float lo_ = bfu_lo(HW_[i_]), hi_ = bfu_hi(HW_[i_]);             \
            ae_ = fmaf(rwe[2 * i_], lo_, ae_);                              \
            e1_ = fmaf(rwe[2 * i_ + 1], hi_, e1_);                          \
            aa_ = fmaf(rwa[2 * i_], lo_, aa_);                              \
            g1_ = fmaf(rwa[2 * i_ + 1], hi_, g1_);                          \
        }                                                                   \
        ae_ = qbf_add(ae_ + e1_);                                           \
        aa_ = qbf_add(aa_ + g1_);
#endif

// ---- G phase: reads w(s), w(s+1) from LDS at phase top (latency hidden) ----
#define SCAN_G(S, LAST)                                                     \
    {                                                                       \
        const float4* wc4_ = (const float4*)&sm.wtabf[(S)][q * 8];          \
        float4 Cw0 = wc4_[0], Cw1 = wc4_[1], Cw2 = wc4_[2], Cw3 = wc4_[3];  \
        float4 Nw0, Nw1, Nw2, Nw3;                                          \
        if (LAST) { Nw0 = Cw0; Nw1 = Cw1; Nw2 = Cw2; Nw3 = Cw3; }           \
        else {                                                              \
            const float4* wn4_ = (const float4*)&sm.wtabf[(S) + 1][q * 8];  \
            Nw0 = wn4_[0]; Nw1 = wn4_[1]; Nw2 = wn4_[2]; Nw3 = wn4_[3];     \
        }                                                                   \
        float wc_[14] = { Cw0.x, Cw0.y, Cw0.z, Cw0.w, Cw1.x, Cw1.y, Cw1.z,  \
                          Cw1.w, Cw2.x, Cw2.y, Cw2.z, Cw2.w, Cw3.x, Cw3.y };\
        float wn_[14] = { Nw0.x, Nw0.y, Nw0.z, Nw0.w, Nw1.x, Nw1.y, Nw1.z,  \
                          Nw1.w, Nw2.x, Nw2.y, Nw2.z, Nw2.w, Nw3.x, Nw3.y };\
        SCAN_G_ACC                                                          \
        float e_ = fast_sigmoid(ae_);                                       \
        float a_ = fast_tanh(aa_);                                          \
        _Pragma("unroll")                                                   \
        for (int m_ = 0; m_ < 14; ++m_)                                     \
            vv[m_] = fmaf(wc_[m_], fmaf(-e_, vv[m_], a_), vv[m_]);          \
        float r0_ = wn_[0] * vv[0], r1_ = wn_[1] * vv[1];                   \
        float r2_ = wn_[2] * vv[2], r3_ = wn_[3] * vv[3];                   \
        r0_ = fmaf(wn_[4],  vv[4],  r0_); r1_ = fmaf(wn_[5],  vv[5],  r1_); \
        r2_ = fmaf(wn_[6],  vv[6],  r2_); r3_ = fmaf(wn_[7],  vv[7],  r3_); \
        r0_ = fmaf(wn_[8],  vv[8],  r0_); r1_ = fmaf(wn_[9],  vv[9],  r1_); \
        r2_ = fmaf(wn_[10], vv[10], r2_); r3_ = fmaf(wn_[11], vv[11], r3_); \
        r0_ = fmaf(wn_[12], vv[12], r0_); r1_ = fmaf(wn_[13], vv[13], r1_); \
        float rr_ = qbf_add((r0_ + r1_) + (r2_ + r3_));                     \
        if (q == 0) sm.xread[d] = f2bf_hw(rr_);                             \
    }

template <bool BF16>
__device__ void scan_impl(
    const int* __restrict__ qseq,
    const void* emb, const void* vu_w1, const void* vu_b1,
    const void* out_w1, const void* out_b1, const void* out_w2, const void* out_b2,
    const unsigned int* wrow_g, const unsigned short* qp_g,
    const f32x2* w2ea_g, const f32x2* eab_g,
    void* outp, SmemB& sm)
{
    const int t = threadIdx.x;
    const int b = blockIdx.x;
    const int l = t & 63;
    const int q = l & 3;
    const int d = ((t >> 6) << 4) + (l >> 2);

    // ---- bulk-load tables into LDS (wtab expanded bf16 -> f32 pairs) ----
    {
        const unsigned int* srcw = wrow_g + (size_t)b * SS * 32;
        f32x2* dstw = (f32x2*)&sm.wtabf[0][0];
        for (int g = t; g < SS * 32; g += 512) {
            unsigned int u = srcw[g];
            f32x2 v; v.x = bfu_lo(u); v.y = bfu_hi(u);
            dstw[g] = v;
        }
        const uint4* srcq = (const uint4*)(qp_g + (size_t)b * SS * DD);
        uint4* dstq = (uint4*)&sm.qptab[0][0];
        for (int g = t; g < SS * DD / 8; g += 512) dstq[g] = srcq[g];
    }

    if (t < 64) {
        int row = qseq[b * SS + (SS - 1)];
        if (BF16) {
            unsigned int uw = ((const unsigned int*)emb)[((size_t)row << 6) + t];
            sm.qlast[2 * t]     = bfu_lo(uw);
            sm.qlast[2 * t + 1] = bfu_hi(uw);
        } else {
            const float* ef = (const float*)emb + (((size_t)row) << 7) + 2 * t;
            sm.qlast[2 * t]     = ef[0];
            sm.qlast[2 * t + 1] = ef[1];
        }
    }

    const float b1r = ldw<BF16>(vu_b1, d);
    const f32x2 eab2 = eab_g[d];

#ifdef HAVE_DOT2BF
    // Packed-bf16 weights: pair i covers k = 32q+2i, 32q+2i+1.
    unsigned int rw1p[16], rwep[16], rwap[16];
#pragma unroll
    for (int i = 0; i < 16; ++i) {
        int k0 = 32 * q + 2 * i;
        rw1p[i] = packbf(ldw<BF16>(vu_w1, (size_t)k0 * DD + d),
                         ldw<BF16>(vu_w1, (size_t)(k0 + 1) * DD + d));
        f32x2 w0v = w2ea_g[(size_t)k0 * DD + d];
        f32x2 w1v = w2ea_g[(size_t)(k0 + 1) * DD + d];
        rwep[i] = packbf(w0v.x, w1v.x);
        rwap[i] = packbf(w0v.y, w1v.y);
    }
#else
    float rw1a[32], rwe[32], rwa[32];
#pragma unroll
    for (int i = 0; i < 32; ++i) {
        rw1a[i] = ldw<BF16>(vu_w1, (size_t)(32 * q + i) * DD + d);
        f32x2 wv = w2ea_g[(size_t)(32 * q + i) * DD + d];
        rwe[i] = wv.x; rwa[i] = wv.y;
    }
#endif

    float vv[14];
#pragma unroll
    for (int m = 0; m < 14; ++m) vv[m] = 0.f;

    if (t < 144) sm.xread[t] = 0;
    __syncthreads();                 // tables + xread visible

    // 99 regular steps + peeled final step (w(s+1) := w(s) reproduces
    // the reference's last_w . vT exactly).
#pragma unroll 2
    for (int s = 0; s < SS - 1; ++s) {
        SCAN_E(s)
        barrier_lgkm();
        SCAN_G(s, false)
        barrier_lgkm();
    }
    SCAN_E(SS - 1)
    barrier_lgkm();
    SCAN_G(SS - 1, true)
    barrier_lgkm();

    // ---- Epilogue (xread is bf16) ----
    float acc = 0.f;
    {
        const uint4* xw4 = (const uint4*)&sm.xread[32 * q];
        uint4 W0 = xw4[0], W1 = xw4[1], W2 = xw4[2], W3 = xw4[3];
        unsigned int XW[16] = { W0.x, W0.y, W0.z, W0.w, W1.x, W1.y, W1.z, W1.w,
                                W2.x, W2.y, W2.z, W2.w, W3.x, W3.y, W3.z, W3.w };
#pragma unroll
        for (int i = 0; i < 16; ++i) {
            int k = 32 * q + 2 * i;
            acc = fmaf(ldw<BF16>(out_w1, (size_t)k * DD + d),       bfu_lo(XW[i]), acc);
            acc = fmaf(ldw<BF16>(out_w1, (size_t)(k + 1) * DD + d), bfu_hi(XW[i]), acc);
        }
        const float4* qp4 = (const float4*)&sm.qlast[32 * q];
#pragma unroll
        for (int j = 0; j < 8; ++j) {
            float4 qv = qp4[j];
            int k = 32 * q + 4 * j;
            acc = fmaf(ldw<BF16>(out_w1, (size_t)(DD + k) * DD + d),     qv.x, acc);
            acc = fmaf(ldw<BF16>(out_w1, (size_t)(DD + k + 1) * DD + d), qv.y, acc);
            acc = fmaf(ldw<BF16>(out_w1, (size_t)(DD + k + 2) * DD + d), qv.z, acc);
            acc = fmaf(ldw<BF16>(out_w1, (size_t)(DD + k + 3) * DD + d), qv.w, acc);
        }
    }
    acc = qbf_add(acc);
    float h1 = fmaxf(acc + ldw<BF16>(out_b1, d), 0.f);
    if (q == 0) sm.h1f[d] = h1;
    __syncthreads();

    if (t < 64) {
        float xs = fmaf(sm.h1f[t], ldw<BF16>(out_w2, t),
                        sm.h1f[64 + t] * ldw<BF16>(out_w2, 64 + t));
#pragma unroll
        for (int o = 32; o > 0; o >>= 1) xs += __shfl_xor(xs, o);
        if (t == 0) {
            float pred = fast_sigmoid(xs + ldw<BF16>(out_b2, 0));
            if (BF16) ((unsigned short*)outp)[b] = f2bf_bits(pred);
            else      ((float*)outp)[b] = pred;
        }
    }
}

__global__ __launch_bounds__(512, 2) void DKVMN_78546361909953_scan(
    const int* __restrict__ qseq,
    const void* emb, const void* vu_w1, const void* vu_b1,
    const void* out_w1, const void* out_b1, const void* out_w2, const void* out_b2,
    void* ws, void* outp)
{
    __shared__ SmemB sm;
    const unsigned int*   wrow_g = (const unsigned int*)((char*)ws + WS_WROW_OFF);
    const unsigned short* qp_g   = (const unsigned short*)((char*)ws + WS_QP_OFF);
    const f32x2*          w2ea_g = (const f32x2*)((char*)ws + WS_W2EA_OFF);
    const f32x2*          eab_g  = (const f32x2*)((char*)ws + WS_EAB_OFF);
    if (detect_bf16(emb))
        scan_impl<true>(qseq, emb, vu_w1, vu_b1, out_w1, out_b1, out_w2, out_b2,
                        wrow_g, qp_g, w2ea_g, eab_g, outp, sm);
    else
        scan_impl<false>(qseq, emb, vu_w1, vu_b1, out_w1, out_b1, out_w2, out_b2,
                         wrow_g, qp_g, w2ea_g, eab_g, outp, sm);
}

// =====================================================================
// Monolithic fallback (r11 verbatim) — used when ws_size < WS_NEED.
// =====================================================================
struct __align__(16) SmemM {
    union {
        struct {
            unsigned int key_w[MM * KROW];
            unsigned int qe8[8][68];
        } pre;
        struct {
            float xread[152];
            float xhdup[312];
            float h1f[DD];
        } run;
    } u;
    union {
        unsigned int w2s[8724];
        struct {
            unsigned int wrow_p[SS][32];
            unsigned short qp_all[SS][DD];
        } tab;
    } v2;
    int qrow[SS];
    float qlast[DD];
};

template <bool BF16>
__device__ void mono_impl(
    const int* __restrict__ qseq,
    const void* emb, const void* key,
    const void* vu_w1, const void* vu_b1, const void* vu_w2, const void* vu_b2,
    const void* er_w, const void* er_b, const void* ad_w, const void* ad_b,
    const void* out_w1, const void* out_b1, const void* out_w2, const void* out_b2,
    void* outp, SmemM& sm)
{
    const int t = threadIdx.x;
    const int b = blockIdx.x;
    const int l = t & 63;
    const int wv = t >> 6;
    const int q = l & 3;
    const int d = (wv << 4) + (l >> 2);

    if (BF16) {
        const unsigned int* kg = (const unsigned int*)key;
        for (int g = t; g < MM * 64; g += 512)
            sm.u.pre.key_w[(g >> 6) * KROW + (g & 63)] = kg[g];
        const unsigned int* wg = (const unsigned int*)vu_w2;
        for (int g = t; g < 128 * 64; g += 512)
            sm.v2.w2s[W2ROW(g >> 6) + (g & 63)] = wg[g];
    } else {
        const float* kf = (const float*)key;
        for (int g = t; g < MM * 64; g += 512) {
            int row = g >> 6, c2 = g & 63;
            sm.u.pre.key_w[row * KROW + c2] = packbf(kf[row * 128 + 2 * c2], kf[row * 128 + 2 * c2 + 1]);
        }
        const float* wf = (const float*)vu_w2;
        for (int g = t; g < 128 * 64; g += 512) {
            int row = g >> 6, c2 = g & 63;
            sm.v2.w2s[W2ROW(row) + c2] = packbf(wf[row * 128 + 2 * c2], wf[row * 128 + 2 * c2 + 1]);
        }
    }
    for (int g = t; g < SS; g += 512) sm.qrow[g] = qseq[b * SS + g];
    __syncthreads();

    f32x2 rw2ea[32];
#pragma unroll
    for (int k = 0; k < 32; ++k) { rw2ea[k].x = 0.f; rw2ea[k].y = 0.f; }
    f32x2 eab2; eab2.x = 0.f; eab2.y = 0.f;
#pragma unroll 1
    for (int jc = 0; jc < 4; ++jc) {
        f32x2 ea[32];
#pragma unroll
        for (int i = 0; i < 32; ++i) {
            int j = 32 * jc + i;
            ea[i].x = ldw<BF16>(er_w, (size_t)j * DD + d);
            ea[i].y = ldw<BF16>(ad_w, (size_t)j * DD + d);
            float b2j = ldw<BF16>(vu_b2, j);
            f32x2 bs; bs.x = b2j; bs.y = b2j;
            eab2 = pkfma(bs, ea[i], eab2);
        }
#pragma unroll
        for (int k = 0; k < 32; ++k) {
            const uint4* wp = (const uint4*)&sm.v2.w2s[W2ROW(32 * q + k) + 16 * jc];
            uint4 A = wp[0], B = wp[1], C = wp[2], Dv = wp[3];
            unsigned int W[16] = { A.x, A.y, A.z, A.w, B.x, B.y, B.z, B.w,
                                   C.x, C.y, C.z, C.w, Dv.x, Dv.y, Dv.z, Dv.w };
            f32x2 acc = rw2ea[k];
#pragma unroll
            for (int wd = 0; wd < 16; ++wd) {
                float wlo = bfu_lo(W[wd]), whi = bfu_hi(W[wd]);
                f32x2 s0; s0.x = wlo; s0.y = wlo;
                f32x2 s1; s1.x = whi; s1.y = whi;
                acc = pkfma(s0, ea[2 * wd], acc);
                acc = pkfma(s1, ea[2 * wd + 1], acc);
            }
            rw2ea[k] = acc;
        }
    }
    eab2.x += ldw<BF16>(er_b, d);
    eab2.y += ldw<BF16>(ad_b, d);
    __syncthreads();

    float rw1a[32], rw1b[32];
#pragma unroll
    for (int i = 0; i < 32; ++i) {
        rw1a[i] = ldw<BF16>(vu_w1, (size_t)(32 * q + i) * DD + d);
        rw1b[i] = ldw<BF16>(vu_w1, (size_t)(DD + 32 * q + i) * DD + d);
    }
    const float b1r = ldw<BF16>(vu_b1, d);

    for (int ii = 0; ii < 13; ++ii) {
        const int nrows = (ii == 12) ? 4 : 8;
        {
            int r = t >> 6, w = t & 63;
            if (r < nrows) {
                int row = sm.qrow[8 * ii + r];
                if (BF16) {
                    sm.u.pre.qe8[r][w] = ((const unsigned int*)emb)[((size_t)row << 6) + w];
                } else {
                    const float* ef = (const float*)emb + (((size_t)row) << 7) + 2 * w;
                    sm.u.pre.qe8[r][w] = packbf(ef[0], ef[1]);
                }
            }
        }
        __syncthreads();

        if (wv < nrows) {
            int m = l;
            int mc = (m < MM) ? m : (MM - 1);
            float a0 = 0.f, a1 = 0.f, a2 = 0.f, a3 = 0.f;
#pragma unroll
            for (int j = 0; j < 32; ++j) {
                uint2 kw = *(const uint2*)&sm.u.pre.key_w[mc * KROW + 2 * j];
                uint2 qw = *(const uint2*)&sm.u.pre.qe8[wv][2 * j];
                a0 = fmaf(bfu_lo(kw.x), bfu_lo(qw.x), a0);
                a1 = fmaf(bfu_hi(kw.x), bfu_hi(qw.x), a1);
                a2 = fmaf(bfu_lo(kw.y), bfu_lo(qw.y), a2);
                a3 = fmaf(bfu_hi(kw.y), bfu_hi(qw.y), a3);
            }
            float lg = (a0 + a1) + (a2 + a3);
            if (m >= MM) lg = -1e30f;
            float mx = lg;
#pragma unroll
            for (int o = 32; o > 0; o >>= 1) mx = fmaxf(mx, __shfl_xor(mx, o));
            float p = (m < MM) ? __expf(lg - mx) : 0.f;
            float sum = p;
#pragma unroll
            for (int o = 32; o > 0; o >>= 1) sum += __shfl_xor(sum, o);
            p = p * fast_rcp(sum);
            float pn = __shfl_xor(p, 4);
            if ((m & 4) == 0)
                sm.v2.tab.wrow_p[8 * ii + wv][(m & 3) * 8 + (m >> 3)] = packbf(p, pn);
        }

        for (int sr = 0; sr < nrows; ++sr) {
            float p0 = 0.f, p1 = 0.f;
#pragma unroll
            for (int i = 0; i < 16; ++i) {
                unsigned int uw = sm.u.pre.qe8[sr][16 * q + i];
                p0 = fmaf(rw1b[2 * i],     bfu_lo(uw), p0);
                p1 = fmaf(rw1b[2 * i + 1], bfu_hi(uw), p1);
            }
            float qpv = qbf_add(p0 + p1);
            if (q == 0) sm.v2.tab.qp_all[8 * ii + sr][d] = f2bf_bits(qpv);
        }
        __syncthreads();
    }

    if (t < 64) {
        unsigned int uw = sm.u.pre.qe8[3][t];
        sm.qlast[2 * t]     = bfu_lo(uw);
        sm.qlast[2 * t + 1] = bfu_hi(uw);
    }
    f32x2 v2[7];
#pragma unroll
    for (int p = 0; p < 7; ++p) { v2[p].x = 0.f; v2[p].y = 0.f; }
    f32x2 wr2[7];
    {
        const uint4* wp = (const uint4*)&sm.v2.tab.wrow_p[0][q * 8];
        uint4 w0 = wp[0], w1 = wp[1];
        unsigned int ww[8] = { w0.x, w0.y, w0.z, w0.w, w1.x, w1.y, w1.z, w1.w };
#pragma unroll
        for (int p = 0; p < 7; ++p) { wr2[p].x = bfu_lo(ww[p]); wr2[p].y = bfu_hi(ww[p]); }
    }
    if (t < 152) sm.u.run.xread[t] = 0.f;
    __syncthreads();

    for (int s = 0; s < SS; ++s) {
        {
            float qpv = bf2f(sm.v2.tab.qp_all[s][d]);
            const float4* xp = (const float4*)&sm.u.run.xread[40 * q];
            f32x2 rw1a2_j;
            f32x2 acc2; acc2.x = 0.f; acc2.y = 0.f;
#pragma unroll
            for (int j = 0; j < 8; ++j) {
                float4 X = xp[j];
                f32x2 x01; x01.x = X.x; x01.y = X.y;
                f32x2 x23; x23.x = X.z; x23.y = X.w;
                rw1a2_j.x = rw1a[4 * j];     rw1a2_j.y = rw1a[4 * j + 1];
                acc2 = pkfma(rw1a2_j, x01, acc2);
                rw1a2_j.x = rw1a[4 * j + 2]; rw1a2_j.y = rw1a[4 * j + 3];
                acc2 = pkfma(rw1a2_j, x23, acc2);
            }
            float acc = qbf_add(acc2.x + acc2.y);
            float hh = fast_tanh(acc + qpv + b1r);
            if (q == 0) {
                f32x2 hd; hd.x = hh; hd.y = hh;
                *(f32x2*)&sm.u.run.xhdup[2 * d + 8 * ((2 * d) >> 5)] = hd;
            }
        }
        __syncthreads();

        {
            f32x2 acc2; acc2.x = 0.f; acc2.y = 0.f;
#pragma unroll
            for (int blk = 0; blk < 2; ++blk) {
                const float4* xp = (const float4*)&sm.u.run.xhdup[80 * q + 40 * blk];
#pragma unroll
                for (int j = 0; j < 8; ++j) {
                    float4 X = xp[j];
                    f32x2 s0; s0.x = X.x; s0.y = X.y;
                    f32x2 s1; s1.x = X.z; s1.y = X.w;
                    int k = 16 * blk + 2 * j;
                    acc2 = pkfma(rw2ea[k], s0, acc2);
                    acc2 = pkfma(rw2ea[k + 1], s1, acc2);
                }
            }
            float ae = qbf_add(acc2.x);
            float aa = qbf_add(acc2.y);
            float e = fast_sigmoid(ae + eab2.x);
            float a = fast_tanh(aa + eab2.y);
            f32x2 me; me.x = -e; me.y = -e;
            f32x2 av; av.x = a;  av.y = a;
#pragma unroll
            for (int p = 0; p < 7; ++p)
                v2[p] = pkfma(wr2[p], pkfma(me, v2[p], av), v2[p]);
            if (s + 1 < SS) {
                const uint4* wp = (const uint4*)&sm.v2.tab.wrow_p[s + 1][q * 8];
                uint4 w0 = wp[0], w1 = wp[1];
                unsigned int ww[8] = { w0.x, w0.y, w0.z, w0.w, w1.x, w1.y, w1.z, w1.w };
#pragma unroll
                for (int p = 0; p < 7; ++p) { wr2[p].x = bfu_lo(ww[p]); wr2[p].y = bfu_hi(ww[p]); }
            }
            f32x2 racc; racc.x = 0.f; racc.y = 0.f;
#pragma unroll
            for (int p = 0; p < 7; ++p)
                racc = pkfma(wr2[p], v2[p], racc);
            float rr = qbf_add(racc.x + racc.y);
            if (q == 0) sm.u.run.xread[d + 8 * (d >> 5)] = rr;
        }
        __syncthreads();
    }

    float acc = 0.f;
    {
        const float4* xp = (const float4*)&sm.u.run.xread[40 * q];
        const float4* qp4 = (const float4*)&sm.qlast[32 * q];
#pragma unroll
        for (int j = 0; j < 8; ++j) {
            float4 xv = xp[j];
            float4 qv = qp4[j];
            int k = 32 * q + 4 * j;
            acc = fmaf(ldw<BF16>(out_w1, (size_t)k * DD + d),       xv.x, acc);
            acc = fmaf(ldw<BF16>(out_w1, (size_t)(k + 1) * DD + d), xv.y, acc);
            acc = fmaf(ldw<BF16>(out_w1, (size_t)(k + 2) * DD + d), xv.z, acc);
            acc = fmaf(ldw<BF16>(out_w1, (size_t)(k + 3) * DD + d), xv.w, acc);
            acc = fmaf(ldw<BF16>(out_w1, (size_t)(DD + k) * DD + d),     qv.x, acc);
            acc = fmaf(ldw<BF16>(out_w1, (size_t)(DD + k + 1) * DD + d), qv.y, acc);
            acc = fmaf(ldw<BF16>(out_w1, (size_t)(DD + k + 2) * DD + d), qv.z, acc);
            acc = fmaf(ldw<BF16>(out_w1, (size_t)(DD + k + 3) * DD + d), qv.w, acc);
        }
    }
    acc = qbf_add(acc);
    float h1 = fmaxf(acc + ldw<BF16>(out_b1, d), 0.f);
    if (q == 0) sm.u.run.h1f[d] = h1;
    __syncthreads();

    if (t < 64) {
        float xs = fmaf(sm.u.run.h1f[t], ldw<BF16>(out_w2, t),
                        sm.u.run.h1f[64 + t] * ldw<BF16>(out_w2, 64 + t));
#pragma unroll
        for (int o = 32; o > 0; o >>= 1) xs += __shfl_xor(xs, o);
        if (t == 0) {
            float pred = fast_sigmoid(xs + ldw<BF16>(out_b2, 0));
            if (BF16) ((unsigned short*)outp)[b] = f2bf_bits(pred);
            else      ((float*)outp)[b] = pred;
        }
    }
}

__global__ __launch_bounds__(512) void DKVMN_78546361909953_kernel(
    const int* __restrict__ qseq,
    const void* emb, const void* key,
    const void* vu_w1, const void* vu_b1, const void* vu_w2, const void* vu_b2,
    const void* er_w, const void* er_b, const void* ad_w, const void* ad_b,
    const void* out_w1, const void* out_b1, const void* out_w2, const void* out_b2,
    void* outp)
{
    __shared__ SmemM sm;
    if (detect_bf16(emb))
        mono_impl<true>(qseq, emb, key, vu_w1, vu_b1, vu_w2, vu_b2,
                        er_w, er_b, ad_w, ad_b, out_w1, out_b1, out_w2, out_b2, outp, sm);
    else
        mono_impl<false>(qseq, emb, key, vu_w1, vu_b1, vu_w2, vu_b2,
                         er_w, er_b, ad_w, ad_b, out_w1, out_b1, out_w2, out_b2, outp, sm);
}

extern "C" void kernel_launch(void* const* d_in, const int* in_sizes, int n_in,
                              void* d_out, int out_size, void* d_ws, size_t ws_size,
                              hipStream_t stream) {
    const int* qseq = (const int*)d_in[0];
    // d_in[1] = answer_seq: unused by the reference
    if (ws_size >= (size_t)WS_NEED) {
        DKVMN_78546361909953_pre<<<dim3(BB + 1, 2), 512, 0, stream>>>(
            qseq, d_in[2], d_in[3], d_in[4],
            d_in[6], d_in[7], d_in[8], d_in[9], d_in[10], d_in[11], d_ws);
        DKVMN_78546361909953_scan<<<BB, 512, 0, stream>>>(
            qseq, d_in[2], d_in[4], d_in[5],
            d_in[12], d_in[13], d_in[14], d_in[15], d_ws, d_out);
    } else {
        DKVMN_78546361909953_kernel<<<BB, 512, 0, stream>>>(
            qseq, d_in[2], d_in[3], d_in[4], d_in[5], d_in[6], d_in[7],
            d_in[8], d_in[9], d_in[10], d_in[11],
            d_in[12], d_in[13], d_in[14], d_in[15], d_out);
    }
}

// Round 7
// 236.792 us; speedup vs baseline: 1.0158x; 1.0158x over previous
//
#include <hip/hip_runtime.h>

// Problem constants (reference: B,S,M,D,NQ = 128,100,50,128,10000)
#define BB 128
#define SS 100
#define MM 50
#define DD 128
#define KROW 66                        // key row stride (u32 words), no overlap

typedef float f32x2 __attribute__((ext_vector_type(2)));

#if defined(__has_builtin)
#  if __has_builtin(__builtin_elementwise_fma)
#    define HAVE_PKFMA 1
#  endif
#  if __has_builtin(__builtin_amdgcn_update_dpp)
#    define HAVE_DPP 1
#  endif
#  if __has_builtin(__builtin_amdgcn_rcpf)
#    define HAVE_RCP 1
#  endif
#  if __has_builtin(__builtin_amdgcn_exp2f)
#    define EXP2(x) __builtin_amdgcn_exp2f(x)
#  endif
#  if __has_builtin(__builtin_amdgcn_fdot2_f32_bf16)
#    define HAVE_DOT2BF 1
#  endif
#endif
#ifndef EXP2
#  define EXP2(x) exp2f(x)
#endif

__device__ __forceinline__ f32x2 pkfma(f32x2 a, f32x2 b, f32x2 c) {
#ifdef HAVE_PKFMA
    return __builtin_elementwise_fma(a, b, c);
#else
    f32x2 r; r.x = fmaf(a.x, b.x, c.x); r.y = fmaf(a.y, b.y, c.y); return r;
#endif
}

__device__ __forceinline__ float qbf_add(float x) {
#ifdef HAVE_DPP
    union { float f; int i; } c, o;
    c.f = x;
    o.i = __builtin_amdgcn_update_dpp(0, c.i, 0xB1, 0xF, 0xF, true);  // quad_perm(1,0,3,2)
    x += o.f;
    c.f = x;
    o.i = __builtin_amdgcn_update_dpp(0, c.i, 0x4E, 0xF, 0xF, true);  // quad_perm(2,3,0,1)
    return x + o.f;
#else
    x += __shfl_xor(x, 1);
    x += __shfl_xor(x, 2);
    return x;
#endif
}

// Block-wide barrier WITHOUT the vmcnt(0) drain that __syncthreads() implies.
__device__ __forceinline__ void barrier_lgkm() {
    asm volatile("s_waitcnt lgkmcnt(0)" ::: "memory");
    __builtin_amdgcn_s_barrier();
    __builtin_amdgcn_sched_barrier(0);   // keep post-barrier ds_reads below the barrier
}

// ---- bf16 helpers ----
__device__ __forceinline__ float bf2f(unsigned short u) {
    union { unsigned int i; float f; } c; c.i = ((unsigned int)u) << 16; return c.f;
}
__device__ __forceinline__ float bfu_lo(unsigned int u) {
    union { unsigned int i; float f; } c; c.i = u << 16; return c.f;
}
__device__ __forceinline__ float bfu_hi(unsigned int u) {
    union { unsigned int i; float f; } c; c.i = u & 0xffff0000u; return c.f;
}
__device__ __forceinline__ unsigned short f2bf_bits(float f) {   // RNE
    union { float f; unsigned int u; } c; c.f = f;
    unsigned int r = (c.u + 0x7FFFu + ((c.u >> 16) & 1u)) >> 16;
    return (unsigned short)r;
}
__device__ __forceinline__ unsigned int packbf(float lo, float hi) {
    return (unsigned int)f2bf_bits(lo) | ((unsigned int)f2bf_bits(hi) << 16);
}
// HW bf16 convert (single v_cvt) where available; software RNE otherwise.
__device__ __forceinline__ unsigned short f2bf_hw(float f) {
#ifdef HAVE_DOT2BF
    union { __bf16 b; unsigned short u; } c; c.b = (__bf16)f; return c.u;
#else
    return f2bf_bits(f);
#endif
}
// v_rcp_f32 (~1 ULP) instead of IEEE divide chain.
__device__ __forceinline__ float fast_rcp(float x) {
#ifdef HAVE_RCP
    return __builtin_amdgcn_rcpf(x);
#else
    return 1.0f / x;
#endif
}
__device__ __forceinline__ float fast_sigmoid(float x) {
    return fast_rcp(1.0f + EXP2(x * -1.4426950408889634f));
}
// 2-term tanh: tanh(x) = 1 - 2/(1+e^{2x}).  Chain: mul -> exp2 -> add -> rcp
// -> fma (no fabs/sub/copysign).  Saturation-safe: exp2 -> inf gives +1,
// exp2 -> 0 gives -1; never NaN.  Numerics verified round 6 (absmax 0.0).
__device__ __forceinline__ float fast_tanh(float x) {
    return fmaf(-2.0f, fast_rcp(1.0f + EXP2(x * 2.8853900817779268f)), 1.0f);
}

#ifdef HAVE_DOT2BF
typedef __bf16 bf2v __attribute__((ext_vector_type(2)));
__device__ __forceinline__ bf2v u2bf(unsigned int u) {
    union { unsigned int x; bf2v v; } c; c.x = u; return c.v;
}
// full-rate 2-way bf16 dot with f32 accumulate: v_dot2_f32_bf16
__device__ __forceinline__ float dot2bf(unsigned int a, unsigned int b, float c) {
    return __builtin_amdgcn_fdot2_f32_bf16(u2bf(a), u2bf(b), c, false);
}
#endif

template <bool BF16>
__device__ __forceinline__ float ldw(const void* p, size_t idx) {
    if (BF16) return bf2f(((const unsigned short*)p)[idx]);
    return ((const float*)p)[idx];
}

__device__ __forceinline__ bool detect_bf16(const void* emb) {
    const unsigned int* eu = (const unsigned int*)emb;
    int cnt = 0;
    for (int i = 0; i < 32; ++i) {
        unsigned int e8 = (eu[i] >> 7) & 0xFFu;
        cnt += (e8 >= 100u && e8 <= 127u) ? 1 : 0;
    }
    return cnt >= 16;
}

#define W2ROW(r) ((r) * 68 + (((r) >> 5) << 3))

// ---- workspace layout (bytes) ----
#define WS_WROW_OFF 0u
#define WS_QP_OFF   (BB * SS * 32u * 4u)                 // 1,638,400
#define WS_W2EA_OFF (WS_QP_OFF + BB * SS * DD * 2u)      // 4,915,200
#define WS_EAB_OFF  (WS_W2EA_OFF + DD * DD * 8u)         // 5,046,272
#define WS_NEED     (WS_EAB_OFF + DD * 8u)               // 5,047,296

// =====================================================================
// Kernel A: grid (129, 2) x 512. Blocks (b<128, half): attention softmax +
// qe-projection for s in [50*half, 50*half+50). Block (128,0): W2EA build.
// =====================================================================
struct __align__(16) SmemA {
    union {
        struct {
            unsigned int key_w[MM * KROW];
            unsigned int qe8[8][68];
        } pre;
        unsigned int w2s[8724];
    } u;
};

template <bool BF16>
__device__ void pre_impl(const int* qseq, const void* emb, const void* key,
                         const void* vu_w1, unsigned int* wrow_g, unsigned short* qp_g,
                         SmemA& sm)
{
    const int t = threadIdx.x;
    const int b = blockIdx.x;
    const int half = blockIdx.y;
    const int l = t & 63;
    const int wv = t >> 6;
    const int q = l & 3;
    const int d = (wv << 4) + (l >> 2);

    if (BF16) {
        const unsigned int* kg = (const unsigned int*)key;
        for (int g = t; g < MM * 64; g += 512)
            sm.u.pre.key_w[(g >> 6) * KROW + (g & 63)] = kg[g];
    } else {
        const float* kf = (const float*)key;
        for (int g = t; g < MM * 64; g += 512) {
            int row = g >> 6, c2 = g & 63;
            sm.u.pre.key_w[row * KROW + c2] = packbf(kf[row * 128 + 2 * c2], kf[row * 128 + 2 * c2 + 1]);
        }
    }

    float rw1b[32];
#pragma unroll
    for (int i = 0; i < 32; ++i)
        rw1b[i] = ldw<BF16>(vu_w1, (size_t)(DD + 32 * q + i) * DD + d);
    __syncthreads();

    for (int ii = 0; ii < 7; ++ii) {
        const int nrows = (ii == 6) ? 2 : 8;
        {
            int r = t >> 6, w = t & 63;
            if (r < nrows) {
                int s = 50 * half + 8 * ii + r;
                int row = qseq[b * SS + s];
                if (BF16) {
                    sm.u.pre.qe8[r][w] = ((const unsigned int*)emb)[((size_t)row << 6) + w];
                } else {
                    const float* ef = (const float*)emb + (((size_t)row) << 7) + 2 * w;
                    sm.u.pre.qe8[r][w] = packbf(ef[0], ef[1]);
                }
            }
        }
        __syncthreads();

        if (wv < nrows) {
            int m = l;
            int mc = (m < MM) ? m : (MM - 1);
            float a0 = 0.f, a1 = 0.f, a2 = 0.f, a3 = 0.f;
#pragma unroll
            for (int j = 0; j < 32; ++j) {
                uint2 kw = *(const uint2*)&sm.u.pre.key_w[mc * KROW + 2 * j];
                uint2 qw = *(const uint2*)&sm.u.pre.qe8[wv][2 * j];
                a0 = fmaf(bfu_lo(kw.x), bfu_lo(qw.x), a0);
                a1 = fmaf(bfu_hi(kw.x), bfu_hi(qw.x), a1);
                a2 = fmaf(bfu_lo(kw.y), bfu_lo(qw.y), a2);
                a3 = fmaf(bfu_hi(kw.y), bfu_hi(qw.y), a3);
            }
            float lg = (a0 + a1) + (a2 + a3);
            if (m >= MM) lg = -1e30f;
            float mx = lg;
#pragma unroll
            for (int o = 32; o > 0; o >>= 1) mx = fmaxf(mx, __shfl_xor(mx, o));
            float p = (m < MM) ? __expf(lg - mx) : 0.f;
            float sum = p;
#pragma unroll
            for (int o = 32; o > 0; o >>= 1) sum += __shfl_xor(sum, o);
            p = p * fast_rcp(sum);
            float pn = __shfl_xor(p, 4);
            int s = 50 * half + 8 * ii + wv;
            if ((m & 4) == 0)
                wrow_g[(size_t)(b * SS + s) * 32 + (m & 3) * 8 + (m >> 3)] = packbf(p, pn);
        }

        for (int sr = 0; sr < nrows; ++sr) {
            float p0 = 0.f, p1 = 0.f;
#pragma unroll
            for (int i = 0; i < 16; ++i) {
                unsigned int uw = sm.u.pre.qe8[sr][16 * q + i];
                p0 = fmaf(rw1b[2 * i],     bfu_lo(uw), p0);
                p1 = fmaf(rw1b[2 * i + 1], bfu_hi(uw), p1);
            }
            float qpv = qbf_add(p0 + p1);
            int s = 50 * half + 8 * ii + sr;
            if (q == 0) qp_g[(size_t)(b * SS + s) * DD + d] = f2bf_bits(qpv);
        }
        __syncthreads();
    }
}

template <bool BF16>
__device__ void build_impl(const void* vu_w2, const void* vu_b2,
                           const void* er_w, const void* er_b,
                           const void* ad_w, const void* ad_b,
                           f32x2* w2ea_g, f32x2* eab_g, SmemA& sm)
{
    const int t = threadIdx.x;
    const int l = t & 63;
    const int wv = t >> 6;
    const int q = l & 3;
    const int d = (wv << 4) + (l >> 2);

    if (BF16) {
        const unsigned int* wg = (const unsigned int*)vu_w2;
        for (int g = t; g < 128 * 64; g += 512)
            sm.u.w2s[W2ROW(g >> 6) + (g & 63)] = wg[g];
    } else {
        const float* wf = (const float*)vu_w2;
        for (int g = t; g < 128 * 64; g += 512) {
            int row = g >> 6, c2 = g & 63;
            sm.u.w2s[W2ROW(row) + c2] = packbf(wf[row * 128 + 2 * c2], wf[row * 128 + 2 * c2 + 1]);
        }
    }
    __syncthreads();

    f32x2 rw2ea[32];
#pragma unroll
    for (int k = 0; k < 32; ++k) { rw2ea[k].x = 0.f; rw2ea[k].y = 0.f; }
    f32x2 eab2; eab2.x = 0.f; eab2.y = 0.f;
#pragma unroll 1
    for (int jc = 0; jc < 4; ++jc) {
        f32x2 ea[32];
#pragma unroll
        for (int i = 0; i < 32; ++i) {
            int j = 32 * jc + i;
            ea[i].x = ldw<BF16>(er_w, (size_t)j * DD + d);
            ea[i].y = ldw<BF16>(ad_w, (size_t)j * DD + d);
            float b2j = ldw<BF16>(vu_b2, j);
            f32x2 bs; bs.x = b2j; bs.y = b2j;
            eab2 = pkfma(bs, ea[i], eab2);
        }
#pragma unroll
        for (int k = 0; k < 32; ++k) {
            const uint4* wp = (const uint4*)&sm.u.w2s[W2ROW(32 * q + k) + 16 * jc];
            uint4 A = wp[0], B = wp[1], C = wp[2], Dv = wp[3];
            unsigned int W[16] = { A.x, A.y, A.z, A.w, B.x, B.y, B.z, B.w,
                                   C.x, C.y, C.z, C.w, Dv.x, Dv.y, Dv.z, Dv.w };
            f32x2 acc = rw2ea[k];
#pragma unroll
            for (int wd = 0; wd < 16; ++wd) {
                float wlo = bfu_lo(W[wd]), whi = bfu_hi(W[wd]);
                f32x2 s0; s0.x = wlo; s0.y = wlo;
                f32x2 s1; s1.x = whi; s1.y = whi;
                acc = pkfma(s0, ea[2 * wd], acc);
                acc = pkfma(s1, ea[2 * wd + 1], acc);
            }
            rw2ea[k] = acc;
        }
    }
    eab2.x += ldw<BF16>(er_b, d);
    eab2.y += ldw<BF16>(ad_b, d);

#pragma unroll
    for (int k = 0; k < 32; ++k)
        w2ea_g[(size_t)(32 * q + k) * DD + d] = rw2ea[k];
    if (q == 0) eab_g[d] = eab2;
}

__global__ __launch_bounds__(512) void DKVMN_78546361909953_pre(
    const int* __restrict__ qseq,
    const void* emb, const void* key, const void* vu_w1,
    const void* vu_w2, const void* vu_b2,
    const void* er_w, const void* er_b, const void* ad_w, const void* ad_b,
    void* ws)
{
    __shared__ SmemA sm;
    unsigned int*   wrow_g = (unsigned int*)((char*)ws + WS_WROW_OFF);
    unsigned short* qp_g   = (unsigned short*)((char*)ws + WS_QP_OFF);
    f32x2*          w2ea_g = (f32x2*)((char*)ws + WS_W2EA_OFF);
    f32x2*          eab_g  = (f32x2*)((char*)ws + WS_EAB_OFF);
    bool isbf = detect_bf16(emb);
    if (blockIdx.x < BB) {
        if (isbf) pre_impl<true>(qseq, emb, key, vu_w1, wrow_g, qp_g, sm);
        else      pre_impl<false>(qseq, emb, key, vu_w1, wrow_g, qp_g, sm);
    } else if (blockIdx.y == 0) {
        if (isbf) build_impl<true>(vu_w2, vu_b2, er_w, er_b, ad_w, ad_b, w2ea_g, eab_g, sm);
        else      build_impl<false>(vu_w2, vu_b2, er_w, er_b, ad_w, ad_b, w2ea_g, eab_g, sm);
    }
}

// =====================================================================
// Kernel B: 128 blocks x 512. Round-4 structure (best measured: 94.6 us)
// + 2-term tanh (round-5's one verified-good chain trim):
//  - wtab expanded to f32 at bulk-load; wr refill = 4x ds_read_b128 issued
//    ONCE per step in E's shadow (round-5's per-G-top double read caused a
//    26x bank-conflict jump and queued ahead of the xh reads -> reverted).
//  - loop unrolled x2 with w-buffer role swap; step 99 peeled.
//  - scalar-FMA state ops; HW bf16 cvt on write tails; dot2 GEMVs.
// =====================================================================
struct __align__(16) SmemB {
    unsigned short xread[144];       // bf16 read vector (128 + pad)
    unsigned short xh[144];          // bf16 h vector
    float h1f[DD];
    float qlast[DD];
    f32x2 wtabf[SS][32];             // expanded attention rows, 25.6 KB
    unsigned short qptab[SS][DD];    // per-step qe-projection (bf16), 25.6 KB
};

// ---- per-path GEMV cores (textual macros; expand inside scan_impl) ----
#ifdef HAVE_DOT2BF
#define SCAN_E(HB)                                                          \
    {                                                                       \
        const uint4* xp_ = (const uint4*)&sm.xread[32 * q];                 \
        uint4 X0 = xp_[0], X1 = xp_[1], X2 = xp_[2], X3 = xp_[3];           \
        float a0_ = dot2bf(rw1p[0],  X0.x, (HB) * 0.25f);                   \
        float a1_ = dot2bf(rw1p[1],  X0.y, 0.f);                            \
        float a2_ = dot2bf(rw1p[2],  X0.z, 0.f);                            \
        float a3_ = dot2bf(rw1p[3],  X0.w, 0.f);                            \
        a0_ = dot2bf(rw1p[4],  X1.x, a0_);                                  \
        a1_ = dot2bf(rw1p[5],  X1.y, a1_);                                  \
        a2_ = dot2bf(rw1p[6],  X1.z, a2_);                                  \
        a3_ = dot2bf(rw1p[7],  X1.w, a3_);                                  \
        a0_ = dot2bf(rw1p[8],  X2.x, a0_);                                  \
        a1_ = dot2bf(rw1p[9],  X2.y, a1_);                                  \
        a2_ = dot2bf(rw1p[10], X2.z, a2_);                                  \
        a3_ = dot2bf(rw1p[11], X2.w, a3_);                                  \
        a0_ = dot2bf(rw1p[12], X3.x, a0_);                                  \
        a1_ = dot2bf(rw1p[13], X3.y, a1_);                                  \
        a2_ = dot2bf(rw1p[14], X3.z, a2_);                                  \
        a3_ = dot2bf(rw1p[15], X3.w, a3_);                                  \
        float u_ = qbf_add((a0_ + a1_) + (a2_ + a3_));                      \
        float hh_ = fast_tanh(u_);                                          \
        if (q == 0) sm.xh[d] = f2bf_hw(hh_);                                \
    }
#define SCAN_G_ACC                                                          \
        const uint4* hp_ = (const uint4*)&sm.xh[32 * q];                    \
        uint4 H0 = hp_[0], H1 = hp_[1], H2 = hp_[2], H3 = hp_[3];           \
        float e0_ = dot2bf(rwep[0],  H0.x, eab2.x * 0.25f);                 \
        float g0_ = dot2bf(rwap[0],  H0.x, eab2.y * 0.25f);                 \
        float e1_ = dot2bf(rwep[1],  H0.y, 0.f);                            \
        float g1_ = dot2bf(rwap[1],  H0.y, 0.f);                            \
        float e2_ = dot2bf(rwep[2],  H0.z, 0.f);                            \
        float g2_ = dot2bf(rwap[2],  H0.z, 0.f);                            \
        float e3_ = dot2bf(rwep[3],  H0.w, 0.f);                            \
        float g3_ = dot2bf(rwap[3],  H0.w, 0.f);                            \
        e0_ = dot2bf(rwep[4],  H1.x, e0_);  g0_ = dot2bf(rwap[4],  H1.x, g0_); \
        e1_ = dot2bf(rwep[5],  H1.y, e1_);  g1_ = dot2bf(rwap[5],  H1.y, g1_); \
        e2_ = dot2bf(rwep[6],  H1.z, e2_);  g2_ = dot2bf(rwap[6],  H1.z, g2_); \
        e3_ = dot2bf(rwep[7],  H1.w, e3_);  g3_ = dot2bf(rwap[7],  H1.w, g3_); \
        e0_ = dot2bf(rwep[8],  H2.x, e0_);  g0_ = dot2bf(rwap[8],  H2.x, g0_); \
        e1_ = dot2bf(rwep[9],  H2.y, e1_);  g1_ = dot2bf(rwap[9],  H2.y, g1_); \
        e2_ = dot2bf(rwep[10], H2.z, e2_);  g2_ = dot2bf(rwap[10], H2.z, g2_); \
        e3_ = dot2bf(rwep[11], H2.w, e3_);  g3_ = dot2bf(rwap[11], H2.w, g3_); \
        e0_ = dot2bf(rwep[12], H3.x, e0_);  g0_ = dot2bf(rwap[12], H3.x, g0_); \
        e1_ = dot2bf(rwep[13], H3.y, e1_);  g1_ = dot2bf(rwap[13], H3.y, g1_); \
        e2_ = dot2bf(rwep[14], H3.z, e2_);  g2_ = dot2bf(rwap[14], H3.z, g2_); \
        e3_ = dot2bf(rwep[15], H3.w, e3_);  g3_ = dot2bf(rwap[15], H3.w, g3_); \
        float ae_ = qbf_add((e0_ + e1_) + (e2_ + e3_));                     \
        float aa_ = qbf_add((g0_ + g1_) + (g2_ + g3_));
#else
#define SCAN_E(HB)                                                          \
    {                                                                       \
        const uint4* xp_ = (const uint4*)&sm.xread[32 * q];                 \
        uint4 X0 = xp_[0], X1 = xp_[1], X2 = xp_[2], X3 = xp_[3];           \
        unsigned int XW_[16] = { X0.x, X0.y, X0.z, X0.w, X1.x, X1.y, X1.z, X1.w, \
                                 X2.x, X2.y, X2.z, X2.w, X3.x, X3.y, X3.z, X3.w }; \
        float a0_ = (HB) * 0.25f, a1_ = 0.f, a2_ = 0.f, a3_ = 0.f;          \
        _Pragma("unroll")                                                   \
        for (int i_ = 0; i_ < 4; ++i_) {                                    \
            a0_ = fmaf(rw1a[8 * i_ + 0], bfu_lo(XW_[4 * i_ + 0]), a0_);     \
            a0_ = fmaf(rw1a[8 * i_ + 1], bfu_hi(XW_[4 * i_ + 0]), a0_);     \
            a1_ = fmaf(rw1a[8 * i_ + 2], bfu_lo(XW_[4 * i_ + 1]), a1_);     \
            a1_ = fmaf(rw1a[8 * i_ + 3], bfu_hi(XW_[4 * i_ + 1]), a1_);     \
            a2_ = fmaf(rw1a[8 * i_ + 4], bfu_lo(XW_[4 * i_ + 2]), a2_);     \
            a2_ = fmaf(rw1a[8 * i_ + 5], bfu_hi(XW_[4 * i_ + 2]), a2_);     \
            a3_ = fmaf(rw1a[8 * i_ + 6], bfu_lo(XW_[4 * i_ + 3]), a3_);     \
            a3_ = fmaf(rw1a[8 * i_ + 7], bfu_hi(XW_[4 * i_ + 3]), a3_);     \
        }                                                                   \
        float u_ = qbf_add((a0_ + a1_) + (a2_ + a3_));                      \
        float hh_ = fast_tanh(u_);                                          \
        if (q == 0) sm.xh[d] = f2bf_hw(hh_);                                \
    }
#define SCAN_G_ACC                                                          \
        const uint4* hp_ = (const uint4*)&sm.xh[32 * q];                    \
        uint4 H0 = hp_[0], H1 = hp_[1], H2 = hp_[2], H3 = hp_[3];           \
        unsigned int HW_[16] = { H0.x, H0.y, H0.z, H0.w, H1.x, H1.y, H1.z, H1.w, \
                                 H2.x, H2.y, H2.z, H2.w, H3.x, H3.y, H3.z, H3.w }; \
        float ae_ = eab2.x * 0.25f, aa_ = eab2.y * 0.25f;                   \
        float e1_ = 0.f, g1_ = 0.f;                                         \
        _Pragma("unroll")                                                   \
        for (int i_ = 0; i_ < 16; ++i_) {                                   \
            float lo_ = bfu_lo(HW_[i_]), hi_ = bfu_hi(HW_[i_]);             \
            ae_ = fmaf(rwe[2 * i_], lo_, ae_);                              \
            e1_ = fmaf(rwe[2 * i_ + 1], hi_, e1_);                          \
            aa_ = fmaf(rwa[2 * i_], lo_, aa_);                              \
            g1_ = fmaf(rwa[2 * i_ + 1], hi_, g1_);                          \
        }                                                                   \
        ae_ = qbf_add(ae_ + e1_);                                           \
        aa_ = qbf_add(aa_ + g1_);
#endif

// ---- one scan step (E + barrier + G + barrier) ----
#define SCAN_STEP(S, WR, WN, LAST)                                          \
    {                                                                       \
        float hb_ = bf2f(qpcur) + b1r;                                      \
        if (!(LAST)) {                                                      \
            const float4* wp4_ = (const float4*)&sm.wtabf[(S) + 1][q * 8];  \
            float4 Aw = wp4_[0], Bw = wp4_[1], Cw = wp4_[2], Dw = wp4_[3];  \
            WN[0] = Aw.x;  WN[1] = Aw.y;  WN[2] = Aw.z;  WN[3] = Aw.w;      \
            WN[4] = Bw.x;  WN[5] = Bw.y;  WN[6] = Bw.z;  WN[7] = Bw.w;      \
            WN[8] = Cw.x;  WN[9] = Cw.y;  WN[10] = Cw.z; WN[11] = Cw.w;     \
            WN[12] = Dw.x; WN[13] = Dw.y;                                   \
            pq = sm.qptab[(S) + 1][d];                                      \
        }                                                                   \
        SCAN_E(hb_)                                                         \
        barrier_lgkm();                                                     \
        {                                                                   \
            SCAN_G_ACC                                                      \
            float e_ = fast_sigmoid(ae_);                                   \
            float a_ = fast_tanh(aa_);                                      \
            _Pragma("unroll")                                               \
            for (int m_ = 0; m_ < 14; ++m_)                                 \
                vv[m_] = fmaf(WR[m_], fmaf(-e_, vv[m_], a_), vv[m_]);       \
            const float* wu_ = (LAST) ? WR : WN;                            \
            float r0_ = wu_[0] * vv[0], r1_ = wu_[1] * vv[1];               \
            float r2_ = wu_[2] * vv[2], r3_ = wu_[3] * vv[3];               \
            r0_ = fmaf(wu_[4],  vv[4],  r0_); r1_ = fmaf(wu_[5],  vv[5],  r1_); \
            r2_ = fmaf(wu_[6],  vv[6],  r2_); r3_ = fmaf(wu_[7],  vv[7],  r3_); \
            r0_ = fmaf(wu_[8],  vv[8],  r0_); r1_ = fmaf(wu_[9],  vv[9],  r1_); \
            r2_ = fmaf(wu_[10], vv[10], r2_); r3_ = fmaf(wu_[11], vv[11], r3_); \
            r0_ = fmaf(wu_[12], vv[12], r0_); r1_ = fmaf(wu_[13], vv[13], r1_); \
            float rr_ = qbf_add((r0_ + r1_) + (r2_ + r3_));                 \
            if (q == 0) sm.xread[d] = f2bf_hw(rr_);                         \
            if (!(LAST)) qpcur = pq;                                        \
        }                                                                   \
        barrier_lgkm();                                                     \
    }

template <bool BF16>
__device__ void scan_impl(
    const int* __restrict__ qseq,
    const void* emb, const void* vu_w1, const void* vu_b1,
    const void* out_w1, const void* out_b1, const void* out_w2, const void* out_b2,
    const unsigned int* wrow_g, const unsigned short* qp_g,
    const f32x2* w2ea_g, const f32x2* eab_g,
    void* outp, SmemB& sm)
{
    const int t = threadIdx.x;
    const int b = blockIdx.x;
    const int l = t & 63;
    const int q = l & 3;
    const int d = ((t >> 6) << 4) + (l >> 2);

    // ---- bulk-load tables into LDS (wtab expanded bf16 -> f32 pairs) ----
    {
        const unsigned int* srcw = wrow_g + (size_t)b * SS * 32;
        f32x2* dstw = (f32x2*)&sm.wtabf[0][0];
        for (int g = t; g < SS * 32; g += 512) {
            unsigned int u = srcw[g];
            f32x2 v; v.x = bfu_lo(u); v.y = bfu_hi(u);
            dstw[g] = v;
        }
        const uint4* srcq = (const uint4*)(qp_g + (size_t)b * SS * DD);
        uint4* dstq = (uint4*)&sm.qptab[0][0];
        for (int g = t; g < SS * DD / 8; g += 512) dstq[g] = srcq[g];
    }

    if (t < 64) {
        int row = qseq[b * SS + (SS - 1)];
        if (BF16) {
            unsigned int uw = ((const unsigned int*)emb)[((size_t)row << 6) + t];
            sm.qlast[2 * t]     = bfu_lo(uw);
            sm.qlast[2 * t + 1] = bfu_hi(uw);
        } else {
            const float* ef = (const float*)emb + (((size_t)row) << 7) + 2 * t;
            sm.qlast[2 * t]     = ef[0];
            sm.qlast[2 * t + 1] = ef[1];
        }
    }

    const float b1r = ldw<BF16>(vu_b1, d);
    const f32x2 eab2 = eab_g[d];

#ifdef HAVE_DOT2BF
    // Packed-bf16 weights: pair i covers k = 32q+2i, 32q+2i+1.
    unsigned int rw1p[16], rwep[16], rwap[16];
#pragma unroll
    for (int i = 0; i < 16; ++i) {
        int k0 = 32 * q + 2 * i;
        rw1p[i] = packbf(ldw<BF16>(vu_w1, (size_t)k0 * DD + d),
                         ldw<BF16>(vu_w1, (size_t)(k0 + 1) * DD + d));
        f32x2 w0v = w2ea_g[(size_t)k0 * DD + d];
        f32x2 w1v = w2ea_g[(size_t)(k0 + 1) * DD + d];
        rwep[i] = packbf(w0v.x, w1v.x);
        rwap[i] = packbf(w0v.y, w1v.y);
    }
#else
    float rw1a[32], rwe[32], rwa[32];
#pragma unroll
    for (int i = 0; i < 32; ++i) {
        rw1a[i] = ldw<BF16>(vu_w1, (size_t)(32 * q + i) * DD + d);
        f32x2 wv = w2ea_g[(size_t)(32 * q + i) * DD + d];
        rwe[i] = wv.x; rwa[i] = wv.y;
    }
#endif

    float vv[14];
#pragma unroll
    for (int m = 0; m < 14; ++m) vv[m] = 0.f;

    if (t < 144) sm.xread[t] = 0;
    __syncthreads();                 // tables + xread visible

    float w0[14], w1[14];
    {
        const float4* wp4 = (const float4*)&sm.wtabf[0][q * 8];
        float4 Aw = wp4[0], Bw = wp4[1], Cw = wp4[2], Dw = wp4[3];
        w0[0] = Aw.x;  w0[1] = Aw.y;  w0[2] = Aw.z;  w0[3] = Aw.w;
        w0[4] = Bw.x;  w0[5] = Bw.y;  w0[6] = Bw.z;  w0[7] = Bw.w;
        w0[8] = Cw.x;  w0[9] = Cw.y;  w0[10] = Cw.z; w0[11] = Cw.w;
        w0[12] = Dw.x; w0[13] = Dw.y;
    }
    unsigned short qpcur = sm.qptab[0][d];
    unsigned short pq = qpcur;

    // 100 steps = 49 full pairs + the pair (98, 99) with step 99 peeled.
    for (int k = 0; k < 49; ++k) {
        SCAN_STEP(2 * k,     w0, w1, false)
        SCAN_STEP(2 * k + 1, w1, w0, false)
    }
    SCAN_STEP(98, w0, w1, false)
    SCAN_STEP(99, w1, w0, true)

    // ---- Epilogue (xread is bf16) ----
    float acc = 0.f;
    {
        const uint4* xw4 = (const uint4*)&sm.xread[32 * q];
        uint4 W0 = xw4[0], W1 = xw4[1], W2 = xw4[2], W3 = xw4[3];
        unsigned int XW[16] = { W0.x, W0.y, W0.z, W0.w, W1.x, W1.y, W1.z, W1.w,
                                W2.x, W2.y, W2.z, W2.w, W3.x, W3.y, W3.z, W3.w };
#pragma unroll
        for (int i = 0; i < 16; ++i) {
            int k = 32 * q + 2 * i;
            acc = fmaf(ldw<BF16>(out_w1, (size_t)k * DD + d),       bfu_lo(XW[i]), acc);
            acc = fmaf(ldw<BF16>(out_w1, (size_t)(k + 1) * DD + d), bfu_hi(XW[i]), acc);
        }
        const float4* qp4 = (const float4*)&sm.qlast[32 * q];
#pragma unroll
        for (int j = 0; j < 8; ++j) {
            float4 qv = qp4[j];
            int k = 32 * q + 4 * j;
            acc = fmaf(ldw<BF16>(out_w1, (size_t)(DD + k) * DD + d),     qv.x, acc);
            acc = fmaf(ldw<BF16>(out_w1, (size_t)(DD + k + 1) * DD + d), qv.y, acc);
            acc = fmaf(ldw<BF16>(out_w1, (size_t)(DD + k + 2) * DD + d), qv.z, acc);
            acc = fmaf(ldw<BF16>(out_w1, (size_t)(DD + k + 3) * DD + d), qv.w, acc);
        }
    }
    acc = qbf_add(acc);
    float h1 = fmaxf(acc + ldw<BF16>(out_b1, d), 0.f);
    if (q == 0) sm.h1f[d] = h1;
    __syncthreads();

    if (t < 64) {
        float xs = fmaf(sm.h1f[t], ldw<BF16>(out_w2, t),
                        sm.h1f[64 + t] * ldw<BF16>(out_w2, 64 + t));
#pragma unroll
        for (int o = 32; o > 0; o >>= 1) xs += __shfl_xor(xs, o);
        if (t == 0) {
            float pred = fast_sigmoid(xs + ldw<BF16>(out_b2, 0));
            if (BF16) ((unsigned short*)outp)[b] = f2bf_bits(pred);
            else      ((float*)outp)[b] = pred;
        }
    }
}

__global__ __launch_bounds__(512, 2) void DKVMN_78546361909953_scan(
    const int* __restrict__ qseq,
    const void* emb, const void* vu_w1, const void* vu_b1,
    const void* out_w1, const void* out_b1, const void* out_w2, const void* out_b2,
    void* ws, void* outp)
{
    __shared__ SmemB sm;
    const unsigned int*   wrow_g = (const unsigned int*)((char*)ws + WS_WROW_OFF);
    const unsigned short* qp_g   = (const unsigned short*)((char*)ws + WS_QP_OFF);
    const f32x2*          w2ea_g = (const f32x2*)((char*)ws + WS_W2EA_OFF);
    const f32x2*          eab_g  = (const f32x2*)((char*)ws + WS_EAB_OFF);
    if (detect_bf16(emb))
        scan_impl<true>(qseq, emb, vu_w1, vu_b1, out_w1, out_b1, out_w2, out_b2,
                        wrow_g, qp_g, w2ea_g, eab_g, outp, sm);
    else
        scan_impl<false>(qseq, emb, vu_w1, vu_b1, out_w1, out_b1, out_w2, out_b2,
                         wrow_g, qp_g, w2ea_g, eab_g, outp, sm);
}

// =====================================================================
// Monolithic fallback (r11 verbatim) — used when ws_size < WS_NEED.
// =====================================================================
struct __align__(16) SmemM {
    union {
        struct {
            unsigned int key_w[MM * KROW];
            unsigned int qe8[8][68];
        } pre;
        struct {
            float xread[152];
            float xhdup[312];
            float h1f[DD];
        } run;
    } u;
    union {
        unsigned int w2s[8724];
        struct {
            unsigned int wrow_p[SS][32];
            unsigned short qp_all[SS][DD];
        } tab;
    } v2;
    int qrow[SS];
    float qlast[DD];
};

template <bool BF16>
__device__ void mono_impl(
    const int* __restrict__ qseq,
    const void* emb, const void* key,
    const void* vu_w1, const void* vu_b1, const void* vu_w2, const void* vu_b2,
    const void* er_w, const void* er_b, const void* ad_w, const void* ad_b,
    const void* out_w1, const void* out_b1, const void* out_w2, const void* out_b2,
    void* outp, SmemM& sm)
{
    const int t = threadIdx.x;
    const int b = blockIdx.x;
    const int l = t & 63;
    const int wv = t >> 6;
    const int q = l & 3;
    const int d = (wv << 4) + (l >> 2);

    if (BF16) {
        const unsigned int* kg = (const unsigned int*)key;
        for (int g = t; g < MM * 64; g += 512)
            sm.u.pre.key_w[(g >> 6) * KROW + (g & 63)] = kg[g];
        const unsigned int* wg = (const unsigned int*)vu_w2;
        for (int g = t; g < 128 * 64; g += 512)
            sm.v2.w2s[W2ROW(g >> 6) + (g & 63)] = wg[g];
    } else {
        const float* kf = (const float*)key;
        for (int g = t; g < MM * 64; g += 512) {
            int row = g >> 6, c2 = g & 63;
            sm.u.pre.key_w[row * KROW + c2] = packbf(kf[row * 128 + 2 * c2], kf[row * 128 + 2 * c2 + 1]);
        }
        const float* wf = (const float*)vu_w2;
        for (int g = t; g < 128 * 64; g += 512) {
            int row = g >> 6, c2 = g & 63;
            sm.v2.w2s[W2ROW(row) + c2] = packbf(wf[row * 128 + 2 * c2], wf[row * 128 + 2 * c2 + 1]);
        }
    }
    for (int g = t; g < SS; g += 512) sm.qrow[g] = qseq[b * SS + g];
    __syncthreads();

    f32x2 rw2ea[32];
#pragma unroll
    for (int k = 0; k < 32; ++k) { rw2ea[k].x = 0.f; rw2ea[k].y = 0.f; }
    f32x2 eab2; eab2.x = 0.f; eab2.y = 0.f;
#pragma unroll 1
    for (int jc = 0; jc < 4; ++jc) {
        f32x2 ea[32];
#pragma unroll
        for (int i = 0; i < 32; ++i) {
            int j = 32 * jc + i;
            ea[i].x = ldw<BF16>(er_w, (size_t)j * DD + d);
            ea[i].y = ldw<BF16>(ad_w, (size_t)j * DD + d);
            float b2j = ldw<BF16>(vu_b2, j);
            f32x2 bs; bs.x = b2j; bs.y = b2j;
            eab2 = pkfma(bs, ea[i], eab2);
        }
#pragma unroll
        for (int k = 0; k < 32; ++k) {
            const uint4* wp = (const uint4*)&sm.v2.w2s[W2ROW(32 * q + k) + 16 * jc];
            uint4 A = wp[0], B = wp[1], C = wp[2], Dv = wp[3];
            unsigned int W[16] = { A.x, A.y, A.z, A.w, B.x, B.y, B.z, B.w,
                                   C.x, C.y, C.z, C.w, Dv.x, Dv.y, Dv.z, Dv.w };
            f32x2 acc = rw2ea[k];
#pragma unroll
            for (int wd = 0; wd < 16; ++wd) {
                float wlo = bfu_lo(W[wd]), whi = bfu_hi(W[wd]);
                f32x2 s0; s0.x = wlo; s0.y = wlo;
                f32x2 s1; s1.x = whi; s1.y = whi;
                acc = pkfma(s0, ea[2 * wd], acc);
                acc = pkfma(s1, ea[2 * wd + 1], acc);
            }
            rw2ea[k] = acc;
        }
    }
    eab2.x += ldw<BF16>(er_b, d);
    eab2.y += ldw<BF16>(ad_b, d);
    __syncthreads();

    float rw1a[32], rw1b[32];
#pragma unroll
    for (int i = 0; i < 32; ++i) {
        rw1a[i] = ldw<BF16>(vu_w1, (size_t)(32 * q + i) * DD + d);
        rw1b[i] = ldw<BF16>(vu_w1, (size_t)(DD + 32 * q + i) * DD + d);
    }
    const float b1r = ldw<BF16>(vu_b1, d);

    for (int ii = 0; ii < 13; ++ii) {
        const int nrows = (ii == 12) ? 4 : 8;
        {
            int r = t >> 6, w = t & 63;
            if (r < nrows) {
                int row = sm.qrow[8 * ii + r];
                if (BF16) {
                    sm.u.pre.qe8[r][w] = ((const unsigned int*)emb)[((size_t)row << 6) + w];
                } else {
                    const float* ef = (const float*)emb + (((size_t)row) << 7) + 2 * w;
                    sm.u.pre.qe8[r][w] = packbf(ef[0], ef[1]);
                }
            }
        }
        __syncthreads();

        if (wv < nrows) {
            int m = l;
            int mc = (m < MM) ? m : (MM - 1);
            float a0 = 0.f, a1 = 0.f, a2 = 0.f, a3 = 0.f;
#pragma unroll
            for (int j = 0; j < 32; ++j) {
                uint2 kw = *(const uint2*)&sm.u.pre.key_w[mc * KROW + 2 * j];
                uint2 qw = *(const uint2*)&sm.u.pre.qe8[wv][2 * j];
                a0 = fmaf(bfu_lo(kw.x), bfu_lo(qw.x), a0);
                a1 = fmaf(bfu_hi(kw.x), bfu_hi(qw.x), a1);
                a2 = fmaf(bfu_lo(kw.y), bfu_lo(qw.y), a2);
                a3 = fmaf(bfu_hi(kw.y), bfu_hi(qw.y), a3);
            }
            float lg = (a0 + a1) + (a2 + a3);
            if (m >= MM) lg = -1e30f;
            float mx = lg;
#pragma unroll
            for (int o = 32; o > 0; o >>= 1) mx = fmaxf(mx, __shfl_xor(mx, o));
            float p = (m < MM) ? __expf(lg - mx) : 0.f;
            float sum = p;
#pragma unroll
            for (int o = 32; o > 0; o >>= 1) sum += __shfl_xor(sum, o);
            p = p * fast_rcp(sum);
            float pn = __shfl_xor(p, 4);
            if ((m & 4) == 0)
                sm.v2.tab.wrow_p[8 * ii + wv][(m & 3) * 8 + (m >> 3)] = packbf(p, pn);
        }

        for (int sr = 0; sr < nrows; ++sr) {
            float p0 = 0.f, p1 = 0.f;
#pragma unroll
            for (int i = 0; i < 16; ++i) {
                unsigned int uw = sm.u.pre.qe8[sr][16 * q + i];
                p0 = fmaf(rw1b[2 * i],     bfu_lo(uw), p0);
                p1 = fmaf(rw1b[2 * i + 1], bfu_hi(uw), p1);
            }
            float qpv = qbf_add(p0 + p1);
            if (q == 0) sm.v2.tab.qp_all[8 * ii + sr][d] = f2bf_bits(qpv);
        }
        __syncthreads();
    }

    if (t < 64) {
        unsigned int uw = sm.u.pre.qe8[3][t];
        sm.qlast[2 * t]     = bfu_lo(uw);
        sm.qlast[2 * t + 1] = bfu_hi(uw);
    }
    f32x2 v2[7];
#pragma unroll
    for (int p = 0; p < 7; ++p) { v2[p].x = 0.f; v2[p].y = 0.f; }
    f32x2 wr2[7];
    {
        const uint4* wp = (const uint4*)&sm.v2.tab.wrow_p[0][q * 8];
        uint4 w0 = wp[0], w1 = wp[1];
        unsigned int ww[8] = { w0.x, w0.y, w0.z, w0.w, w1.x, w1.y, w1.z, w1.w };
#pragma unroll
        for (int p = 0; p < 7; ++p) { wr2[p].x = bfu_lo(ww[p]); wr2[p].y = bfu_hi(ww[p]); }
    }
    if (t < 152) sm.u.run.xread[t] = 0.f;
    __syncthreads();

    for (int s = 0; s < SS; ++s) {
        {
            float qpv = bf2f(sm.v2.tab.qp_all[s][d]);
            const float4* xp = (const float4*)&sm.u.run.xread[40 * q];
            f32x2 rw1a2_j;
            f32x2 acc2; acc2.x = 0.f; acc2.y = 0.f;
#pragma unroll
            for (int j = 0; j < 8; ++j) {
                float4 X = xp[j];
                f32x2 x01; x01.x = X.x; x01.y = X.y;
                f32x2 x23; x23.x = X.z; x23.y = X.w;
                rw1a2_j.x = rw1a[4 * j];     rw1a2_j.y = rw1a[4 * j + 1];
                acc2 = pkfma(rw1a2_j, x01, acc2);
                rw1a2_j.x = rw1a[4 * j + 2]; rw1a2_j.y = rw1a[4 * j + 3];
                acc2 = pkfma(rw1a2_j, x23, acc2);
            }
            float acc = qbf_add(acc2.x + acc2.y);
            float hh = fast_tanh(acc + qpv + b1r);
            if (q == 0) {
                f32x2 hd; hd.x = hh; hd.y = hh;
                *(f32x2*)&sm.u.run.xhdup[2 * d + 8 * ((2 * d) >> 5)] = hd;
            }
        }
        __syncthreads();

        {
            f32x2 acc2; acc2.x = 0.f; acc2.y = 0.f;
#pragma unroll
            for (int blk = 0; blk < 2; ++blk) {
                const float4* xp = (const float4*)&sm.u.run.xhdup[80 * q + 40 * blk];
#pragma unroll
                for (int j = 0; j < 8; ++j) {
                    float4 X = xp[j];
                    f32x2 s0; s0.x = X.x; s0.y = X.y;
                    f32x2 s1; s1.x = X.z; s1.y = X.w;
                    int k = 16 * blk + 2 * j;
                    acc2 = pkfma(rw2ea[k], s0, acc2);
                    acc2 = pkfma(rw2ea[k + 1], s1, acc2);
                }
            }
            float ae = qbf_add(acc2.x);
            float aa = qbf_add(acc2.y);
            float e = fast_sigmoid(ae + eab2.x);
            float a = fast_tanh(aa + eab2.y);
            f32x2 me; me.x = -e; me.y = -e;
            f32x2 av; av.x = a;  av.y = a;
#pragma unroll
            for (int p = 0; p < 7; ++p)
                v2[p] = pkfma(wr2[p], pkfma(me, v2[p], av), v2[p]);
            if (s + 1 < SS) {
                const uint4* wp = (const uint4*)&sm.v2.tab.wrow_p[s + 1][q * 8];
                uint4 w0 = wp[0], w1 = wp[1];
                unsigned int ww[8] = { w0.x, w0.y, w0.z, w0.w, w1.x, w1.y, w1.z, w1.w };
#pragma unroll
                for (int p = 0; p < 7; ++p) { wr2[p].x = bfu_lo(ww[p]); wr2[p].y = bfu_hi(ww[p]); }
            }
            f32x2 racc; racc.x = 0.f; racc.y = 0.f;
#pragma unroll
            for (int p = 0; p < 7; ++p)
                racc = pkfma(wr2[p], v2[p], racc);
            float rr = qbf_add(racc.x + racc.y);
            if (q == 0) sm.u.run.xread[d + 8 * (d >> 5)] = rr;
        }
        __syncthreads();
    }

    float acc = 0.f;
    {
        const float4* xp = (const float4*)&sm.u.run.xread[40 * q];
        const float4* qp4 = (const float4*)&sm.qlast[32 * q];
#pragma unroll
        for (int j = 0; j < 8; ++j) {
            float4 xv = xp[j];
            float4 qv = qp4[j];
            int k = 32 * q + 4 * j;
            acc = fmaf(ldw<BF16>(out_w1, (size_t)k * DD + d),       xv.x, acc);
            acc = fmaf(ldw<BF16>(out_w1, (size_t)(k + 1) * DD + d), xv.y, acc);
            acc = fmaf(ldw<BF16>(out_w1, (size_t)(k + 2) * DD + d), xv.z, acc);
            acc = fmaf(ldw<BF16>(out_w1, (size_t)(k + 3) * DD + d), xv.w, acc);
            acc = fmaf(ldw<BF16>(out_w1, (size_t)(DD + k) * DD + d),     qv.x, acc);
            acc = fmaf(ldw<BF16>(out_w1, (size_t)(DD + k + 1) * DD + d), qv.y, acc);
            acc = fmaf(ldw<BF16>(out_w1, (size_t)(DD + k + 2) * DD + d), qv.z, acc);
            acc = fmaf(ldw<BF16>(out_w1, (size_t)(DD + k + 3) * DD + d), qv.w, acc);
        }
    }
    acc = qbf_add(acc);
    float h1 = fmaxf(acc + ldw<BF16>(out_b1, d), 0.f);
    if (q == 0) sm.u.run.h1f[d] = h1;
    __syncthreads();

    if (t < 64) {
        float xs = fmaf(sm.u.run.h1f[t], ldw<BF16>(out_w2, t),
                        sm.u.run.h1f[64 + t] * ldw<BF16>(out_w2, 64 + t));
#pragma unroll
        for (int o = 32; o > 0; o >>= 1) xs += __shfl_xor(xs, o);
        if (t == 0) {
            float pred = fast_sigmoid(xs + ldw<BF16>(out_b2, 0));
            if (BF16) ((unsigned short*)outp)[b] = f2bf_bits(pred);
            else      ((float*)outp)[b] = pred;
        }
    }
}

__global__ __launch_bounds__(512) void DKVMN_78546361909953_kernel(
    const int* __restrict__ qseq,
    const void* emb, const void* key,
    const void* vu_w1, const void* vu_b1, const void* vu_w2, const void* vu_b2,
    const void* er_w, const void* er_b, const void* ad_w, const void* ad_b,
    const void* out_w1, const void* out_b1, const void* out_w2, const void* out_b2,
    void* outp)
{
    __shared__ SmemM sm;
    if (detect_bf16(emb))
        mono_impl<true>(qseq, emb, key, vu_w1, vu_b1, vu_w2, vu_b2,
                        er_w, er_b, ad_w, ad_b, out_w1, out_b1, out_w2, out_b2, outp, sm);
    else
        mono_impl<false>(qseq, emb, key, vu_w1, vu_b1, vu_w2, vu_b2,
                         er_w, er_b, ad_w, ad_b, out_w1, out_b1, out_w2, out_b2, outp, sm);
}

extern "C" void kernel_launch(void* const* d_in, const int* in_sizes, int n_in,
                              void* d_out, int out_size, void* d_ws, size_t ws_size,
                              hipStream_t stream) {
    const int* qseq = (const int*)d_in[0];
    // d_in[1] = answer_seq: unused by the reference
    if (ws_size >= (size_t)WS_NEED) {
        DKVMN_78546361909953_pre<<<dim3(BB + 1, 2), 512, 0, stream>>>(
            qseq, d_in[2], d_in[3], d_in[4],
            d_in[6], d_in[7], d_in[8], d_in[9], d_in[10], d_in[11], d_ws);
        DKVMN_78546361909953_scan<<<BB, 512, 0, stream>>>(
            qseq, d_in[2], d_in[4], d_in[5],
            d_in[12], d_in[13], d_in[14], d_in[15], d_ws, d_out);
    } else {
        DKVMN_78546361909953_kernel<<<BB, 512, 0, stream>>>(
            qseq, d_in[2], d_in[3], d_in[4], d_in[5], d_in[6], d_in[7],
            d_in[8], d_in[9], d_in[10], d_in[11],
            d_in[12], d_in[13], d_in[14], d_in[15], d_out);
    }
}